// Round 10
// baseline (436.942 us; speedup 1.0000x reference)
//
#include <hip/hip_runtime.h>

#define N_NODES 100000
#define N_EDGES 3200000
#define N_GRAPHS 1024
#define NCLS 21
#define NBKT 196          // buckets of 512 nodes
#define NB 512            // streaming blocks for hist/bin
#define CHUNK 6250        // N_EDGES / NB
#define SCAN_N (NBKT*NB)  // 100352
#define SCAN_NB1 98       // SCAN_N / 1024
#define BUF_CAP 24576     // 96KB LDS edge buffer

typedef short s8v __attribute__((ext_vector_type(8)));
typedef float f4v __attribute__((ext_vector_type(4)));

__device__ __forceinline__ float bf2f(unsigned short u) {
    return __uint_as_float(((unsigned)u) << 16);
}
__device__ __forceinline__ unsigned short f2bf(float f) {
    unsigned u = __float_as_uint(f);
    unsigned r = 0x7fffu + ((u >> 16) & 1u);   // RNE
    return (unsigned short)((u + r) >> 16);
}

// ---- per-graph node counts: batch is SORTED -> binary search ----
__global__ void k_gcnt(const int* __restrict__ batch, float* __restrict__ gcnt) {
    int g = blockIdx.x * 256 + threadIdx.x;
    if (g >= N_GRAPHS) return;
    int lo = 0, hi = N_NODES;
    while (lo < hi) { int m = (lo + hi) >> 1; if (batch[m] < g) lo = m + 1; else hi = m; }
    int lo2 = lo, hi2 = N_NODES;
    while (lo2 < hi2) { int m = (lo2 + hi2) >> 1; if (batch[m] < g + 1) lo2 = m + 1; else hi2 = m; }
    gcnt[g] = (float)(lo2 - lo);
}

// ---- pack W2=[W2l;W2r] (128x64) into bf16 B-fragment order ----
// frag i = kstep*4+nt; element (L,j): B[k][n], k=kstep*32+(L>>4)*8+j, n=nt*16+(L&15)
__global__ void k_wprep(const float* __restrict__ W2l, const float* __restrict__ W2r,
                        unsigned short* __restrict__ wp) {
    int tid = blockIdx.x * 256 + threadIdx.x;   // 8192 total
    int frag = tid >> 9;
    int r = tid & 511;
    int L = r >> 3, j = r & 7;
    int kstep = frag >> 2, nt = frag & 3;
    int k = kstep * 32 + (L >> 4) * 8 + j;
    int n = nt * 16 + (L & 15);
    float val = (k < 64) ? W2l[k * 64 + n] : W2r[(k - 64) * 64 + n];
    wp[tid] = f2bf(val);
}

// ---- per-block bucket histogram ----
__global__ __launch_bounds__(256) void k_hist(const int* __restrict__ dst,
                                              int* __restrict__ gh) {
    __shared__ int lh[NBKT];
    for (int i = threadIdx.x; i < NBKT; i += 256) lh[i] = 0;
    __syncthreads();
    int e0 = blockIdx.x * CHUNK;
    for (int e = e0 + threadIdx.x; e < e0 + CHUNK; e += 256)
        atomicAdd(&lh[dst[e] >> 9], 1);
    __syncthreads();
    for (int i = threadIdx.x; i < NBKT; i += 256) gh[i * NB + blockIdx.x] = lh[i];
}

// ---- exclusive scan over gh, in place ----
__global__ void k_scan1(int* __restrict__ buf, int* __restrict__ bsum) {
    __shared__ int lds[256];
    int t = threadIdx.x;
    int base = blockIdx.x * 1024 + t * 4;
    int v[4];
#pragma unroll
    for (int i = 0; i < 4; i++) v[i] = buf[base + i];
    int tsum = v[0] + v[1] + v[2] + v[3];
    lds[t] = tsum;
    __syncthreads();
    for (int off = 1; off < 256; off <<= 1) {
        int cur = lds[t];
        int add = (t >= off) ? lds[t - off] : 0;
        __syncthreads();
        lds[t] = cur + add;
        __syncthreads();
    }
    int run = lds[t] - tsum;
#pragma unroll
    for (int i = 0; i < 4; i++) { buf[base + i] = run; run += v[i]; }
    if (t == 255) bsum[blockIdx.x] = lds[255];
}

__global__ void k_scan2(int* __restrict__ bsum) {
    if (threadIdx.x == 0 && blockIdx.x == 0) {
        int acc = 0;
        for (int b = 0; b < SCAN_NB1; b++) { int t = bsum[b]; bsum[b] = acc; acc += t; }
    }
}

__global__ void k_scan3(int* __restrict__ buf, const int* __restrict__ bsum) {
    int i = blockIdx.x * 256 + threadIdx.x;
    if (i < SCAN_N) buf[i] += bsum[i >> 10];
}

// ---- bin edges into bucket-grouped runs ----
__global__ __launch_bounds__(256) void k_bin(const int* __restrict__ src,
                                             const int* __restrict__ dst,
                                             const int* __restrict__ S,
                                             unsigned int* __restrict__ bins) {
    __shared__ int cur[NBKT];
    for (int i = threadIdx.x; i < NBKT; i += 256) cur[i] = S[i * NB + blockIdx.x];
    __syncthreads();
    int e0 = blockIdx.x * CHUNK;
    for (int e = e0 + threadIdx.x; e < e0 + CHUNK; e += 256) {
        int dd = dst[e];
        int pos = atomicAdd(&cur[dd >> 9], 1);
        bins[pos] = ((unsigned)src[e] << 9) | (unsigned)(dd & 511);
    }
}

// ---- per-bucket: LDS slurp -> hist -> scan -> row[] + in-place exact CSR ----
__global__ __launch_bounds__(256) void k_build(const int* __restrict__ S,
                                               unsigned int* __restrict__ bins,
                                               int* __restrict__ row) {
    __shared__ unsigned int ebuf[BUF_CAP];
    __shared__ int hist[512];
    __shared__ int curs[512];
    __shared__ int lds[256];
    int k = blockIdx.x, t = threadIdx.x;
    int e0 = S[k * NB];
    int e1 = (k == NBKT - 1) ? N_EDGES : S[(k + 1) * NB];
    int cnt = min(e1 - e0, BUF_CAP);
    hist[t] = 0; hist[t + 256] = 0;
    __syncthreads();
    for (int i = t; i < cnt; i += 256) {
        unsigned p = bins[e0 + i];
        ebuf[i] = p;
        atomicAdd(&hist[p & 511u], 1);
    }
    __syncthreads();
    int h0 = hist[2 * t], h1 = hist[2 * t + 1];
    lds[t] = h0 + h1;
    __syncthreads();
    for (int off = 1; off < 256; off <<= 1) {
        int cur = lds[t];
        int add = (t >= off) ? lds[t - off] : 0;
        __syncthreads();
        lds[t] = cur + add;
        __syncthreads();
    }
    int run = e0 + lds[t] - (h0 + h1);
    curs[2 * t] = run;
    curs[2 * t + 1] = run + h0;
    int n0 = k * 512 + 2 * t;
    if (n0 < N_NODES) row[n0] = run;
    if (n0 + 1 < N_NODES) row[n0 + 1] = run + h0;
    if (k == NBKT - 1 && t == 255) row[N_NODES] = N_EDGES;
    __syncthreads();
    for (int i = t; i < cnt; i += 256) {
        unsigned p = ebuf[i];
        int pos = atomicAdd(&curs[p & 511u], 1);
        bins[pos] = p >> 9;
    }
}

// ---- layer 1 aggregate: thread per node ----
__global__ __launch_bounds__(256) void k_agg1(
    const int* __restrict__ row, const unsigned int* __restrict__ csr,
    const float* __restrict__ x, float* __restrict__ agg1) {
    int n = blockIdx.x * 256 + threadIdx.x;
    if (n >= N_NODES) return;
    int r0 = row[n], r1 = row[n + 1];
    float s = 0.0f;
    int j = r0;
    for (; j + 4 <= r1; j += 4) {
        int a0 = (int)csr[j + 0];
        int a1 = (int)csr[j + 1];
        int a2 = (int)csr[j + 2];
        int a3 = (int)csr[j + 3];
        float v0 = x[a0], v1 = x[a1], v2 = x[a2], v3 = x[a3];
        s += (v0 + v1) + (v2 + v3);
    }
    for (; j < r1; ++j) s += x[csr[j]];
    agg1[n] = s / fmaxf((float)(r1 - r0), 1.0f);
}

// ---- layer 1 node update: elementwise -> h1b (bf16) ----
__global__ __launch_bounds__(256) void k_h1(
    const float* __restrict__ agg1, const float* __restrict__ x,
    const float* __restrict__ W1l, const float* __restrict__ b1,
    const float* __restrict__ W1r, unsigned short* __restrict__ h1b) {
    int i = blockIdx.x * 256 + threadIdx.x;
    int n = i >> 6, f = i & 63;
    float v = agg1[n] * W1l[f] + b1[f] + x[n] * W1r[f];
    h1b[i] = f2bf(fmaxf(v, 0.0f));
}

// ---- layer 2 gather: wave per node, register accumulate ----
__global__ __launch_bounds__(256) void k_gather2(
    const int* __restrict__ row, const unsigned int* __restrict__ csr,
    const unsigned short* __restrict__ h1b,
    unsigned short* __restrict__ agg2b) {
    int gw = (blockIdx.x * 256 + threadIdx.x) >> 6;
    int f = threadIdx.x & 63;
    int nw = gridDim.x * 4;
    for (int n = gw; n < N_NODES; n += nw) {
        int r0 = row[n], r1 = row[n + 1];
        float s = 0.0f;
        for (int base = r0; base < r1; base += 64) {
            int idx = base + f;
            int vs = (idx < r1) ? (int)csr[idx] : 0;
            int c = min(64, r1 - base);
            int j = 0;
            for (; j + 8 <= c; j += 8) {
                int a0 = __builtin_amdgcn_readlane(vs, j + 0);
                int a1 = __builtin_amdgcn_readlane(vs, j + 1);
                int a2 = __builtin_amdgcn_readlane(vs, j + 2);
                int a3 = __builtin_amdgcn_readlane(vs, j + 3);
                int a4 = __builtin_amdgcn_readlane(vs, j + 4);
                int a5 = __builtin_amdgcn_readlane(vs, j + 5);
                int a6 = __builtin_amdgcn_readlane(vs, j + 6);
                int a7 = __builtin_amdgcn_readlane(vs, j + 7);
                float v0 = bf2f(h1b[(size_t)a0 * 64 + f]);
                float v1 = bf2f(h1b[(size_t)a1 * 64 + f]);
                float v2 = bf2f(h1b[(size_t)a2 * 64 + f]);
                float v3 = bf2f(h1b[(size_t)a3 * 64 + f]);
                float v4 = bf2f(h1b[(size_t)a4 * 64 + f]);
                float v5 = bf2f(h1b[(size_t)a5 * 64 + f]);
                float v6 = bf2f(h1b[(size_t)a6 * 64 + f]);
                float v7 = bf2f(h1b[(size_t)a7 * 64 + f]);
                s += ((v0 + v1) + (v2 + v3)) + ((v4 + v5) + (v6 + v7));
            }
            for (; j < c; ++j) {
                int aj = __builtin_amdgcn_readlane(vs, j);
                s += bf2f(h1b[(size_t)aj * 64 + f]);
            }
        }
        float m = s / fmaxf((float)(r1 - r0), 1.0f);
        agg2b[(size_t)n * 64 + f] = f2bf(m);
    }
}

// ---- layer 2 GEMM via MFMA: [16 nodes x 128] x [128 x 64] per wave ----
__global__ __launch_bounds__(256) void k_gemv_mfma(
    const unsigned short* __restrict__ agg2b, const unsigned short* __restrict__ h1b,
    const unsigned short* __restrict__ wp, const float* __restrict__ b2,
    unsigned short* __restrict__ h2b) {
    int L = threadIdx.x & 63;
    int wid = threadIdx.x >> 6;
    int n0 = blockIdx.x * 64 + wid * 16;
    if (n0 >= N_NODES) return;
    int m = L & 15, q = L >> 4;
    int nrow = min(n0 + m, N_NODES - 1);

    // B fragments (named -> registers, no scratch)
#define LOADB(i) s8v B##i = *(const s8v*)(wp + (i) * 512 + L * 8)
    LOADB(0); LOADB(1); LOADB(2); LOADB(3);
    LOADB(4); LOADB(5); LOADB(6); LOADB(7);
    LOADB(8); LOADB(9); LOADB(10); LOADB(11);
    LOADB(12); LOADB(13); LOADB(14); LOADB(15);
#undef LOADB

    const s8v a0 = *(const s8v*)(agg2b + (size_t)nrow * 64 + q * 8);
    const s8v a1 = *(const s8v*)(agg2b + (size_t)nrow * 64 + 32 + q * 8);
    const s8v a2 = *(const s8v*)(h1b   + (size_t)nrow * 64 + q * 8);
    const s8v a3 = *(const s8v*)(h1b   + (size_t)nrow * 64 + 32 + q * 8);

    f4v acc0 = {0.f, 0.f, 0.f, 0.f}, acc1 = acc0, acc2 = acc0, acc3 = acc0;
    acc0 = __builtin_amdgcn_mfma_f32_16x16x32_bf16(a0, B0,  acc0, 0, 0, 0);
    acc0 = __builtin_amdgcn_mfma_f32_16x16x32_bf16(a1, B4,  acc0, 0, 0, 0);
    acc0 = __builtin_amdgcn_mfma_f32_16x16x32_bf16(a2, B8,  acc0, 0, 0, 0);
    acc0 = __builtin_amdgcn_mfma_f32_16x16x32_bf16(a3, B12, acc0, 0, 0, 0);
    acc1 = __builtin_amdgcn_mfma_f32_16x16x32_bf16(a0, B1,  acc1, 0, 0, 0);
    acc1 = __builtin_amdgcn_mfma_f32_16x16x32_bf16(a1, B5,  acc1, 0, 0, 0);
    acc1 = __builtin_amdgcn_mfma_f32_16x16x32_bf16(a2, B9,  acc1, 0, 0, 0);
    acc1 = __builtin_amdgcn_mfma_f32_16x16x32_bf16(a3, B13, acc1, 0, 0, 0);
    acc2 = __builtin_amdgcn_mfma_f32_16x16x32_bf16(a0, B2,  acc2, 0, 0, 0);
    acc2 = __builtin_amdgcn_mfma_f32_16x16x32_bf16(a1, B6,  acc2, 0, 0, 0);
    acc2 = __builtin_amdgcn_mfma_f32_16x16x32_bf16(a2, B10, acc2, 0, 0, 0);
    acc2 = __builtin_amdgcn_mfma_f32_16x16x32_bf16(a3, B14, acc2, 0, 0, 0);
    acc3 = __builtin_amdgcn_mfma_f32_16x16x32_bf16(a0, B3,  acc3, 0, 0, 0);
    acc3 = __builtin_amdgcn_mfma_f32_16x16x32_bf16(a1, B7,  acc3, 0, 0, 0);
    acc3 = __builtin_amdgcn_mfma_f32_16x16x32_bf16(a2, B11, acc3, 0, 0, 0);
    acc3 = __builtin_amdgcn_mfma_f32_16x16x32_bf16(a3, B15, acc3, 0, 0, 0);

    // D layout: col = L&15 (feature within tile), row = q*4 + reg (node)
    int fcol = L & 15;
    float bia0 = b2[fcol], bia1 = b2[16 + fcol], bia2 = b2[32 + fcol], bia3 = b2[48 + fcol];
    int rbase = n0 + q * 4;
#pragma unroll
    for (int r = 0; r < 4; r++) {
        int n = rbase + r;
        if (n < N_NODES) {
            size_t o = (size_t)n * 64 + fcol;
            h2b[o]      = f2bf(fmaxf(acc0[r] + bia0, 0.0f));
            h2b[o + 16] = f2bf(fmaxf(acc1[r] + bia1, 0.0f));
            h2b[o + 32] = f2bf(fmaxf(acc2[r] + bia2, 0.0f));
            h2b[o + 48] = f2bf(fmaxf(acc3[r] + bia3, 0.0f));
        }
    }
}

// ---- mean-pool: wave per 512-node run, flush on graph change ----
__global__ __launch_bounds__(256) void k_pool(
    const unsigned short* __restrict__ h2b, const int* __restrict__ batch,
    const float* __restrict__ gcnt, float* __restrict__ pooled) {
    int w = (blockIdx.x * 256 + threadIdx.x) >> 6;
    int f = threadIdx.x & 63;
    int nbeg = w * 512;
    if (nbeg >= N_NODES) return;
    int nend = min(nbeg + 512, N_NODES);
    int prevb = batch[nbeg];
    float acc = 0.0f;
    for (int n = nbeg; n < nend; n++) {
        int b = batch[n];
        float v = bf2f(h2b[(size_t)n * 64 + f]);
        if (b != prevb) {
            atomicAdd(&pooled[prevb * 64 + f], acc / fmaxf(gcnt[prevb], 1.0f));
            prevb = b;
            acc = v;
        } else {
            acc += v;
        }
    }
    atomicAdd(&pooled[prevb * 64 + f], acc / fmaxf(gcnt[prevb], 1.0f));
}

// ---- classifier ----
__global__ void k_cls(const float* __restrict__ pooled, const float* __restrict__ Wc,
                      const float* __restrict__ bc, float* __restrict__ out) {
    __shared__ float rowv[64];
    int g = blockIdx.x;
    int f = threadIdx.x;
    rowv[f] = pooled[g * 64 + f];
    __syncthreads();
    if (f < NCLS) {
        float acc = bc[f];
#pragma unroll
        for (int kk = 0; kk < 64; kk++) acc += rowv[kk] * Wc[kk * NCLS + f];
        out[g * NCLS + f] = acc;
    }
}

extern "C" void kernel_launch(void* const* d_in, const int* in_sizes, int n_in,
                              void* d_out, int out_size, void* d_ws, size_t ws_size,
                              hipStream_t stream) {
    const float* x     = (const float*)d_in[0];
    const int*   eidx  = (const int*)d_in[1];
    const int*   batch = (const int*)d_in[2];
    const float* W1l   = (const float*)d_in[3];
    const float* b1    = (const float*)d_in[4];
    const float* W1r   = (const float*)d_in[5];
    const float* W2l   = (const float*)d_in[6];
    const float* b2    = (const float*)d_in[7];
    const float* W2r   = (const float*)d_in[8];
    const float* Wc    = (const float*)d_in[9];
    const float* bc    = (const float*)d_in[10];
    float* out = (float*)d_out;

    const int* src = eidx;
    const int* dst = eidx + N_EDGES;

    // workspace ≈ 39.9 MB (proven-safe envelope 40.67 MB)
    char* p = (char*)d_ws;
    unsigned int* bins    = (unsigned int*)p;   p += (size_t)N_EDGES * 4;        // 12.8 MB
    unsigned short* h1b   = (unsigned short*)p; p += (size_t)N_NODES * 64 * 2;   // 12.8 MB
    unsigned short* agg2b = (unsigned short*)p; p += (size_t)N_NODES * 64 * 2;   // 12.8 MB
    int* gh    = (int*)p;                       p += (size_t)SCAN_N * 4;         // 0.40 MB
    int* bsum  = (int*)p;                       p += 128 * 4;
    int* row   = (int*)p;                       p += (size_t)(N_NODES + 1) * 4;  // 0.40 MB
    float* agg1= (float*)p;                     p += (size_t)N_NODES * 4;        // 0.40 MB
    float* gcnt= (float*)p;                     p += N_GRAPHS * 4;
    unsigned short* wp = (unsigned short*)p;    p += 8192 * 2;                   // 16 KB
    // ---- zeroed region ----
    float* pooled = (float*)p;                  p += (size_t)N_GRAPHS * 64 * 4;
    size_t zero_bytes = (size_t)(N_GRAPHS * 64) * 4;

    // h2b aliases bins: bins is dead after k_gather2
    unsigned short* h2b = (unsigned short*)bins;

    hipMemsetAsync(pooled, 0, zero_bytes, stream);

    k_gcnt <<<(N_GRAPHS + 255) / 256, 256, 0, stream>>>(batch, gcnt);
    k_wprep<<<32, 256, 0, stream>>>(W2l, W2r, wp);
    k_hist <<<NB, 256, 0, stream>>>(dst, gh);
    k_scan1<<<SCAN_NB1, 256, 0, stream>>>(gh, bsum);
    k_scan2<<<1, 64, 0, stream>>>(bsum);
    k_scan3<<<(SCAN_N + 255) / 256, 256, 0, stream>>>(gh, bsum);
    k_bin  <<<NB, 256, 0, stream>>>(src, dst, gh, bins);
    k_build<<<NBKT, 256, 0, stream>>>(gh, bins, row);

    k_agg1     <<<(N_NODES + 255) / 256, 256, 0, stream>>>(row, bins, x, agg1);
    k_h1       <<<(N_NODES * 64) / 256, 256, 0, stream>>>(agg1, x, W1l, b1, W1r, h1b);
    k_gather2  <<<2048, 256, 0, stream>>>(row, bins, h1b, agg2b);
    k_gemv_mfma<<<(N_NODES + 63) / 64, 256, 0, stream>>>(agg2b, h1b, wp, b2, h2b);
    k_pool     <<<49, 256, 0, stream>>>(h2b, batch, gcnt, pooled);
    k_cls      <<<N_GRAPHS, 64, 0, stream>>>(pooled, Wc, bc, out);
}

// Round 11
// 290.005 us; speedup vs baseline: 1.5067x; 1.5067x over previous
//
#include <hip/hip_runtime.h>

#define N_NODES 100000
#define N_EDGES 3200000
#define N_GRAPHS 1024
#define NCLS 21
#define NBKT 196          // buckets of 512 nodes
#define NB 512            // streaming blocks for hist/bin
#define CHUNK 6250        // N_EDGES / NB
#define SCAN_N (NBKT*NB)  // 100352
#define SCAN_NB1 98       // SCAN_N / 1024
#define BUF_CAP 24576     // 96KB LDS edge buffer

typedef short s8v __attribute__((ext_vector_type(8)));
typedef float f4v __attribute__((ext_vector_type(4)));

__device__ __forceinline__ float bf2f(unsigned short u) {
    return __uint_as_float(((unsigned)u) << 16);
}
__device__ __forceinline__ unsigned short f2bf(float f) {
    unsigned u = __float_as_uint(f);
    unsigned r = 0x7fffu + ((u >> 16) & 1u);   // RNE
    return (unsigned short)((u + r) >> 16);
}

// ---- graph start offsets: batch is SORTED -> binary search ----
__global__ void k_gstart(const int* __restrict__ batch, int* __restrict__ gstart) {
    int g = blockIdx.x * 256 + threadIdx.x;
    if (g > N_GRAPHS) return;
    if (g == N_GRAPHS) { gstart[N_GRAPHS] = N_NODES; return; }
    int lo = 0, hi = N_NODES;
    while (lo < hi) { int m = (lo + hi) >> 1; if (batch[m] < g) lo = m + 1; else hi = m; }
    gstart[g] = lo;
}

// ---- pack W2=[W2l;W2r] (128x64) into bf16 B-fragment order ----
__global__ void k_wprep(const float* __restrict__ W2l, const float* __restrict__ W2r,
                        unsigned short* __restrict__ wp) {
    int tid = blockIdx.x * 256 + threadIdx.x;   // 8192 total
    int frag = tid >> 9;
    int r = tid & 511;
    int L = r >> 3, j = r & 7;
    int kstep = frag >> 2, nt = frag & 3;
    int k = kstep * 32 + (L >> 4) * 8 + j;
    int n = nt * 16 + (L & 15);
    float val = (k < 64) ? W2l[k * 64 + n] : W2r[(k - 64) * 64 + n];
    wp[tid] = f2bf(val);
}

// ---- per-block bucket histogram ----
__global__ __launch_bounds__(256) void k_hist(const int* __restrict__ dst,
                                              int* __restrict__ gh) {
    __shared__ int lh[NBKT];
    for (int i = threadIdx.x; i < NBKT; i += 256) lh[i] = 0;
    __syncthreads();
    int e0 = blockIdx.x * CHUNK;
    for (int e = e0 + threadIdx.x; e < e0 + CHUNK; e += 256)
        atomicAdd(&lh[dst[e] >> 9], 1);
    __syncthreads();
    for (int i = threadIdx.x; i < NBKT; i += 256) gh[i * NB + blockIdx.x] = lh[i];
}

// ---- exclusive scan over gh, in place ----
__global__ void k_scan1(int* __restrict__ buf, int* __restrict__ bsum) {
    __shared__ int lds[256];
    int t = threadIdx.x;
    int base = blockIdx.x * 1024 + t * 4;
    int v[4];
#pragma unroll
    for (int i = 0; i < 4; i++) v[i] = buf[base + i];
    int tsum = v[0] + v[1] + v[2] + v[3];
    lds[t] = tsum;
    __syncthreads();
    for (int off = 1; off < 256; off <<= 1) {
        int cur = lds[t];
        int add = (t >= off) ? lds[t - off] : 0;
        __syncthreads();
        lds[t] = cur + add;
        __syncthreads();
    }
    int run = lds[t] - tsum;
#pragma unroll
    for (int i = 0; i < 4; i++) { buf[base + i] = run; run += v[i]; }
    if (t == 255) bsum[blockIdx.x] = lds[255];
}

__global__ void k_scan2(int* __restrict__ bsum) {
    if (threadIdx.x == 0 && blockIdx.x == 0) {
        int acc = 0;
        for (int b = 0; b < SCAN_NB1; b++) { int t = bsum[b]; bsum[b] = acc; acc += t; }
    }
}

__global__ void k_scan3(int* __restrict__ buf, const int* __restrict__ bsum) {
    int i = blockIdx.x * 256 + threadIdx.x;
    if (i < SCAN_N) buf[i] += bsum[i >> 10];
}

// ---- bin edges into bucket-grouped runs ----
__global__ __launch_bounds__(256) void k_bin(const int* __restrict__ src,
                                             const int* __restrict__ dst,
                                             const int* __restrict__ S,
                                             unsigned int* __restrict__ bins) {
    __shared__ int cur[NBKT];
    for (int i = threadIdx.x; i < NBKT; i += 256) cur[i] = S[i * NB + blockIdx.x];
    __syncthreads();
    int e0 = blockIdx.x * CHUNK;
    for (int e = e0 + threadIdx.x; e < e0 + CHUNK; e += 256) {
        int dd = dst[e];
        int pos = atomicAdd(&cur[dd >> 9], 1);
        bins[pos] = ((unsigned)src[e] << 9) | (unsigned)(dd & 511);
    }
}

// ---- per-bucket: LDS slurp -> hist -> scan -> row[] + in-place exact CSR ----
__global__ __launch_bounds__(256) void k_build(const int* __restrict__ S,
                                               unsigned int* __restrict__ bins,
                                               int* __restrict__ row) {
    __shared__ unsigned int ebuf[BUF_CAP];
    __shared__ int hist[512];
    __shared__ int curs[512];
    __shared__ int lds[256];
    int k = blockIdx.x, t = threadIdx.x;
    int e0 = S[k * NB];
    int e1 = (k == NBKT - 1) ? N_EDGES : S[(k + 1) * NB];
    int cnt = min(e1 - e0, BUF_CAP);
    hist[t] = 0; hist[t + 256] = 0;
    __syncthreads();
    for (int i = t; i < cnt; i += 256) {
        unsigned p = bins[e0 + i];
        ebuf[i] = p;
        atomicAdd(&hist[p & 511u], 1);
    }
    __syncthreads();
    int h0 = hist[2 * t], h1 = hist[2 * t + 1];
    lds[t] = h0 + h1;
    __syncthreads();
    for (int off = 1; off < 256; off <<= 1) {
        int cur = lds[t];
        int add = (t >= off) ? lds[t - off] : 0;
        __syncthreads();
        lds[t] = cur + add;
        __syncthreads();
    }
    int run = e0 + lds[t] - (h0 + h1);
    curs[2 * t] = run;
    curs[2 * t + 1] = run + h0;
    int n0 = k * 512 + 2 * t;
    if (n0 < N_NODES) row[n0] = run;
    if (n0 + 1 < N_NODES) row[n0 + 1] = run + h0;
    if (k == NBKT - 1 && t == 255) row[N_NODES] = N_EDGES;
    __syncthreads();
    for (int i = t; i < cnt; i += 256) {
        unsigned p = ebuf[i];
        int pos = atomicAdd(&curs[p & 511u], 1);
        bins[pos] = p >> 9;
    }
}

// ---- layer 1 aggregate: thread per node ----
__global__ __launch_bounds__(256) void k_agg1(
    const int* __restrict__ row, const unsigned int* __restrict__ csr,
    const float* __restrict__ x, float* __restrict__ agg1) {
    int n = blockIdx.x * 256 + threadIdx.x;
    if (n >= N_NODES) return;
    int r0 = row[n], r1 = row[n + 1];
    float s = 0.0f;
    int j = r0;
    for (; j + 4 <= r1; j += 4) {
        int a0 = (int)csr[j + 0];
        int a1 = (int)csr[j + 1];
        int a2 = (int)csr[j + 2];
        int a3 = (int)csr[j + 3];
        float v0 = x[a0], v1 = x[a1], v2 = x[a2], v3 = x[a3];
        s += (v0 + v1) + (v2 + v3);
    }
    for (; j < r1; ++j) s += x[csr[j]];
    agg1[n] = s / fmaxf((float)(r1 - r0), 1.0f);
}

// ---- layer 1 node update: elementwise -> h1b (bf16) ----
__global__ __launch_bounds__(256) void k_h1(
    const float* __restrict__ agg1, const float* __restrict__ x,
    const float* __restrict__ W1l, const float* __restrict__ b1,
    const float* __restrict__ W1r, unsigned short* __restrict__ h1b) {
    int i = blockIdx.x * 256 + threadIdx.x;
    int n = i >> 6, f = i & 63;
    float v = agg1[n] * W1l[f] + b1[f] + x[n] * W1r[f];
    h1b[i] = f2bf(fmaxf(v, 0.0f));
}

// ---- layer 2 gather: wave per node, register accumulate ----
__global__ __launch_bounds__(256) void k_gather2(
    const int* __restrict__ row, const unsigned int* __restrict__ csr,
    const unsigned short* __restrict__ h1b,
    unsigned short* __restrict__ agg2b) {
    int gw = (blockIdx.x * 256 + threadIdx.x) >> 6;
    int f = threadIdx.x & 63;
    int nw = gridDim.x * 4;
    for (int n = gw; n < N_NODES; n += nw) {
        int r0 = row[n], r1 = row[n + 1];
        float s = 0.0f;
        for (int base = r0; base < r1; base += 64) {
            int idx = base + f;
            int vs = (idx < r1) ? (int)csr[idx] : 0;
            int c = min(64, r1 - base);
            int j = 0;
            for (; j + 8 <= c; j += 8) {
                int a0 = __builtin_amdgcn_readlane(vs, j + 0);
                int a1 = __builtin_amdgcn_readlane(vs, j + 1);
                int a2 = __builtin_amdgcn_readlane(vs, j + 2);
                int a3 = __builtin_amdgcn_readlane(vs, j + 3);
                int a4 = __builtin_amdgcn_readlane(vs, j + 4);
                int a5 = __builtin_amdgcn_readlane(vs, j + 5);
                int a6 = __builtin_amdgcn_readlane(vs, j + 6);
                int a7 = __builtin_amdgcn_readlane(vs, j + 7);
                float v0 = bf2f(h1b[(size_t)a0 * 64 + f]);
                float v1 = bf2f(h1b[(size_t)a1 * 64 + f]);
                float v2 = bf2f(h1b[(size_t)a2 * 64 + f]);
                float v3 = bf2f(h1b[(size_t)a3 * 64 + f]);
                float v4 = bf2f(h1b[(size_t)a4 * 64 + f]);
                float v5 = bf2f(h1b[(size_t)a5 * 64 + f]);
                float v6 = bf2f(h1b[(size_t)a6 * 64 + f]);
                float v7 = bf2f(h1b[(size_t)a7 * 64 + f]);
                s += ((v0 + v1) + (v2 + v3)) + ((v4 + v5) + (v6 + v7));
            }
            for (; j < c; ++j) {
                int aj = __builtin_amdgcn_readlane(vs, j);
                s += bf2f(h1b[(size_t)aj * 64 + f]);
            }
        }
        float m = s / fmaxf((float)(r1 - r0), 1.0f);
        agg2b[(size_t)n * 64 + f] = f2bf(m);
    }
}

// ---- layer 2 GEMM via MFMA: [16 nodes x 128] x [128 x 64] per wave ----
__global__ __launch_bounds__(256) void k_gemv_mfma(
    const unsigned short* __restrict__ agg2b, const unsigned short* __restrict__ h1b,
    const unsigned short* __restrict__ wp, const float* __restrict__ b2,
    unsigned short* __restrict__ h2b) {
    int L = threadIdx.x & 63;
    int wid = threadIdx.x >> 6;
    int n0 = blockIdx.x * 64 + wid * 16;
    if (n0 >= N_NODES) return;
    int m = L & 15, q = L >> 4;
    int nrow = min(n0 + m, N_NODES - 1);

#define LOADB(i) s8v B##i = *(const s8v*)(wp + (i) * 512 + L * 8)
    LOADB(0); LOADB(1); LOADB(2); LOADB(3);
    LOADB(4); LOADB(5); LOADB(6); LOADB(7);
    LOADB(8); LOADB(9); LOADB(10); LOADB(11);
    LOADB(12); LOADB(13); LOADB(14); LOADB(15);
#undef LOADB

    const s8v a0 = *(const s8v*)(agg2b + (size_t)nrow * 64 + q * 8);
    const s8v a1 = *(const s8v*)(agg2b + (size_t)nrow * 64 + 32 + q * 8);
    const s8v a2 = *(const s8v*)(h1b   + (size_t)nrow * 64 + q * 8);
    const s8v a3 = *(const s8v*)(h1b   + (size_t)nrow * 64 + 32 + q * 8);

    f4v acc0 = {0.f, 0.f, 0.f, 0.f}, acc1 = acc0, acc2 = acc0, acc3 = acc0;
    acc0 = __builtin_amdgcn_mfma_f32_16x16x32_bf16(a0, B0,  acc0, 0, 0, 0);
    acc0 = __builtin_amdgcn_mfma_f32_16x16x32_bf16(a1, B4,  acc0, 0, 0, 0);
    acc0 = __builtin_amdgcn_mfma_f32_16x16x32_bf16(a2, B8,  acc0, 0, 0, 0);
    acc0 = __builtin_amdgcn_mfma_f32_16x16x32_bf16(a3, B12, acc0, 0, 0, 0);
    acc1 = __builtin_amdgcn_mfma_f32_16x16x32_bf16(a0, B1,  acc1, 0, 0, 0);
    acc1 = __builtin_amdgcn_mfma_f32_16x16x32_bf16(a1, B5,  acc1, 0, 0, 0);
    acc1 = __builtin_amdgcn_mfma_f32_16x16x32_bf16(a2, B9,  acc1, 0, 0, 0);
    acc1 = __builtin_amdgcn_mfma_f32_16x16x32_bf16(a3, B13, acc1, 0, 0, 0);
    acc2 = __builtin_amdgcn_mfma_f32_16x16x32_bf16(a0, B2,  acc2, 0, 0, 0);
    acc2 = __builtin_amdgcn_mfma_f32_16x16x32_bf16(a1, B6,  acc2, 0, 0, 0);
    acc2 = __builtin_amdgcn_mfma_f32_16x16x32_bf16(a2, B10, acc2, 0, 0, 0);
    acc2 = __builtin_amdgcn_mfma_f32_16x16x32_bf16(a3, B14, acc2, 0, 0, 0);
    acc3 = __builtin_amdgcn_mfma_f32_16x16x32_bf16(a0, B3,  acc3, 0, 0, 0);
    acc3 = __builtin_amdgcn_mfma_f32_16x16x32_bf16(a1, B7,  acc3, 0, 0, 0);
    acc3 = __builtin_amdgcn_mfma_f32_16x16x32_bf16(a2, B11, acc3, 0, 0, 0);
    acc3 = __builtin_amdgcn_mfma_f32_16x16x32_bf16(a3, B15, acc3, 0, 0, 0);

    int fcol = L & 15;
    float bia0 = b2[fcol], bia1 = b2[16 + fcol], bia2 = b2[32 + fcol], bia3 = b2[48 + fcol];
    int rbase = n0 + q * 4;
#pragma unroll
    for (int r = 0; r < 4; r++) {
        int n = rbase + r;
        if (n < N_NODES) {
            size_t o = (size_t)n * 64 + fcol;
            h2b[o]      = f2bf(fmaxf(acc0[r] + bia0, 0.0f));
            h2b[o + 16] = f2bf(fmaxf(acc1[r] + bia1, 0.0f));
            h2b[o + 32] = f2bf(fmaxf(acc2[r] + bia2, 0.0f));
            h2b[o + 48] = f2bf(fmaxf(acc3[r] + bia3, 0.0f));
        }
    }
}

// ---- mean-pool: 4 waves per graph, branch-free strided accumulate ----
__global__ __launch_bounds__(256) void k_pool2(
    const unsigned short* __restrict__ h2b, const int* __restrict__ gstart,
    float* __restrict__ pooled) {
    int w = (blockIdx.x * 256 + threadIdx.x) >> 6;   // global wave id
    int f = threadIdx.x & 63;
    int g = w >> 2;
    int q = w & 3;
    if (g >= N_GRAPHS) return;
    int ns = gstart[g], ne = gstart[g + 1];
    float s = 0.0f;
    int n = ns + q;
    for (; n + 12 < ne; n += 16) {   // 4 independent loads in flight
        float v0 = bf2f(h2b[(size_t)(n)      * 64 + f]);
        float v1 = bf2f(h2b[(size_t)(n + 4)  * 64 + f]);
        float v2 = bf2f(h2b[(size_t)(n + 8)  * 64 + f]);
        float v3 = bf2f(h2b[(size_t)(n + 12) * 64 + f]);
        s += (v0 + v1) + (v2 + v3);
    }
    for (; n < ne; n += 4) s += bf2f(h2b[(size_t)n * 64 + f]);
    atomicAdd(&pooled[g * 64 + f], s / fmaxf((float)(ne - ns), 1.0f));
}

// ---- classifier ----
__global__ void k_cls(const float* __restrict__ pooled, const float* __restrict__ Wc,
                      const float* __restrict__ bc, float* __restrict__ out) {
    __shared__ float rowv[64];
    int g = blockIdx.x;
    int f = threadIdx.x;
    rowv[f] = pooled[g * 64 + f];
    __syncthreads();
    if (f < NCLS) {
        float acc = bc[f];
#pragma unroll
        for (int kk = 0; kk < 64; kk++) acc += rowv[kk] * Wc[kk * NCLS + f];
        out[g * NCLS + f] = acc;
    }
}

extern "C" void kernel_launch(void* const* d_in, const int* in_sizes, int n_in,
                              void* d_out, int out_size, void* d_ws, size_t ws_size,
                              hipStream_t stream) {
    const float* x     = (const float*)d_in[0];
    const int*   eidx  = (const int*)d_in[1];
    const int*   batch = (const int*)d_in[2];
    const float* W1l   = (const float*)d_in[3];
    const float* b1    = (const float*)d_in[4];
    const float* W1r   = (const float*)d_in[5];
    const float* W2l   = (const float*)d_in[6];
    const float* b2    = (const float*)d_in[7];
    const float* W2r   = (const float*)d_in[8];
    const float* Wc    = (const float*)d_in[9];
    const float* bc    = (const float*)d_in[10];
    float* out = (float*)d_out;

    const int* src = eidx;
    const int* dst = eidx + N_EDGES;

    // workspace ≈ 39.9 MB (proven-safe envelope 40.67 MB)
    char* p = (char*)d_ws;
    unsigned int* bins    = (unsigned int*)p;   p += (size_t)N_EDGES * 4;        // 12.8 MB
    unsigned short* h1b   = (unsigned short*)p; p += (size_t)N_NODES * 64 * 2;   // 12.8 MB
    unsigned short* agg2b = (unsigned short*)p; p += (size_t)N_NODES * 64 * 2;   // 12.8 MB
    int* gh    = (int*)p;                       p += (size_t)SCAN_N * 4;         // 0.40 MB
    int* bsum  = (int*)p;                       p += 128 * 4;
    int* row   = (int*)p;                       p += (size_t)(N_NODES + 1) * 4;  // 0.40 MB
    float* agg1= (float*)p;                     p += (size_t)N_NODES * 4;        // 0.40 MB
    int* gstart= (int*)p;                       p += (N_GRAPHS + 1) * 4;
    unsigned short* wp = (unsigned short*)p;    p += 8192 * 2;                   // 16 KB
    // ---- zeroed region ----
    float* pooled = (float*)p;                  p += (size_t)N_GRAPHS * 64 * 4;
    size_t zero_bytes = (size_t)(N_GRAPHS * 64) * 4;

    // h2b aliases bins: bins is dead after k_gather2
    unsigned short* h2b = (unsigned short*)bins;

    hipMemsetAsync(pooled, 0, zero_bytes, stream);

    k_gstart<<<(N_GRAPHS + 256) / 256, 256, 0, stream>>>(batch, gstart);
    k_wprep<<<32, 256, 0, stream>>>(W2l, W2r, wp);
    k_hist <<<NB, 256, 0, stream>>>(dst, gh);
    k_scan1<<<SCAN_NB1, 256, 0, stream>>>(gh, bsum);
    k_scan2<<<1, 64, 0, stream>>>(bsum);
    k_scan3<<<(SCAN_N + 255) / 256, 256, 0, stream>>>(gh, bsum);
    k_bin  <<<NB, 256, 0, stream>>>(src, dst, gh, bins);
    k_build<<<NBKT, 256, 0, stream>>>(gh, bins, row);

    k_agg1     <<<(N_NODES + 255) / 256, 256, 0, stream>>>(row, bins, x, agg1);
    k_h1       <<<(N_NODES * 64) / 256, 256, 0, stream>>>(agg1, x, W1l, b1, W1r, h1b);
    k_gather2  <<<2048, 256, 0, stream>>>(row, bins, h1b, agg2b);
    k_gemv_mfma<<<(N_NODES + 63) / 64, 256, 0, stream>>>(agg2b, h1b, wp, b2, h2b);
    k_pool2    <<<(N_GRAPHS * 4 * 64) / 256, 256, 0, stream>>>(h2b, gstart, pooled);
    k_cls      <<<N_GRAPHS, 64, 0, stream>>>(pooled, Wc, bc, out);
}

// Round 12
// 279.927 us; speedup vs baseline: 1.5609x; 1.0360x over previous
//
#include <hip/hip_runtime.h>

#define N_NODES 100000
#define N_EDGES 3200000
#define N_GRAPHS 1024
#define NCLS 21
#define NBKT 196          // buckets of 512 nodes
#define NB 512            // streaming blocks for hist/bin
#define CHUNK 6250        // N_EDGES / NB
#define SCAN_N (NBKT*NB)  // 100352
#define SCAN_NB1 98       // SCAN_N / 1024
#define BUF_CAP 24576     // 96KB LDS edge buffer

typedef short s8v __attribute__((ext_vector_type(8)));
typedef float f4v __attribute__((ext_vector_type(4)));

__device__ __forceinline__ float bf2f(unsigned short u) {
    return __uint_as_float(((unsigned)u) << 16);
}
__device__ __forceinline__ unsigned short f2bf(float f) {
    unsigned u = __float_as_uint(f);
    unsigned r = 0x7fffu + ((u >> 16) & 1u);   // RNE
    return (unsigned short)((u + r) >> 16);
}
__device__ __forceinline__ float lo2f(unsigned w) { return __uint_as_float(w << 16); }
__device__ __forceinline__ float hi2f(unsigned w) { return __uint_as_float(w & 0xffff0000u); }

// ---- graph start offsets: batch is SORTED -> binary search ----
__global__ void k_gstart(const int* __restrict__ batch, int* __restrict__ gstart) {
    int g = blockIdx.x * 256 + threadIdx.x;
    if (g > N_GRAPHS) return;
    if (g == N_GRAPHS) { gstart[N_GRAPHS] = N_NODES; return; }
    int lo = 0, hi = N_NODES;
    while (lo < hi) { int m = (lo + hi) >> 1; if (batch[m] < g) lo = m + 1; else hi = m; }
    gstart[g] = lo;
}

// ---- pack W2=[W2l;W2r] (128x64) into bf16 B-fragment order ----
__global__ void k_wprep(const float* __restrict__ W2l, const float* __restrict__ W2r,
                        unsigned short* __restrict__ wp) {
    int tid = blockIdx.x * 256 + threadIdx.x;   // 8192 total
    int frag = tid >> 9;
    int r = tid & 511;
    int L = r >> 3, j = r & 7;
    int kstep = frag >> 2, nt = frag & 3;
    int k = kstep * 32 + (L >> 4) * 8 + j;
    int n = nt * 16 + (L & 15);
    float val = (k < 64) ? W2l[k * 64 + n] : W2r[(k - 64) * 64 + n];
    wp[tid] = f2bf(val);
}

// ---- per-block bucket histogram ----
__global__ __launch_bounds__(256) void k_hist(const int* __restrict__ dst,
                                              int* __restrict__ gh) {
    __shared__ int lh[NBKT];
    for (int i = threadIdx.x; i < NBKT; i += 256) lh[i] = 0;
    __syncthreads();
    int e0 = blockIdx.x * CHUNK;
    for (int e = e0 + threadIdx.x; e < e0 + CHUNK; e += 256)
        atomicAdd(&lh[dst[e] >> 9], 1);
    __syncthreads();
    for (int i = threadIdx.x; i < NBKT; i += 256) gh[i * NB + blockIdx.x] = lh[i];
}

// ---- exclusive scan over gh, in place ----
__global__ void k_scan1(int* __restrict__ buf, int* __restrict__ bsum) {
    __shared__ int lds[256];
    int t = threadIdx.x;
    int base = blockIdx.x * 1024 + t * 4;
    int v[4];
#pragma unroll
    for (int i = 0; i < 4; i++) v[i] = buf[base + i];
    int tsum = v[0] + v[1] + v[2] + v[3];
    lds[t] = tsum;
    __syncthreads();
    for (int off = 1; off < 256; off <<= 1) {
        int cur = lds[t];
        int add = (t >= off) ? lds[t - off] : 0;
        __syncthreads();
        lds[t] = cur + add;
        __syncthreads();
    }
    int run = lds[t] - tsum;
#pragma unroll
    for (int i = 0; i < 4; i++) { buf[base + i] = run; run += v[i]; }
    if (t == 255) bsum[blockIdx.x] = lds[255];
}

__global__ void k_scan2(int* __restrict__ bsum) {
    if (threadIdx.x == 0 && blockIdx.x == 0) {
        int acc = 0;
        for (int b = 0; b < SCAN_NB1; b++) { int t = bsum[b]; bsum[b] = acc; acc += t; }
    }
}

__global__ void k_scan3(int* __restrict__ buf, const int* __restrict__ bsum) {
    int i = blockIdx.x * 256 + threadIdx.x;
    if (i < SCAN_N) buf[i] += bsum[i >> 10];
}

// ---- bin edges into bucket-grouped runs ----
__global__ __launch_bounds__(256) void k_bin(const int* __restrict__ src,
                                             const int* __restrict__ dst,
                                             const int* __restrict__ S,
                                             unsigned int* __restrict__ bins) {
    __shared__ int cur[NBKT];
    for (int i = threadIdx.x; i < NBKT; i += 256) cur[i] = S[i * NB + blockIdx.x];
    __syncthreads();
    int e0 = blockIdx.x * CHUNK;
    for (int e = e0 + threadIdx.x; e < e0 + CHUNK; e += 256) {
        int dd = dst[e];
        int pos = atomicAdd(&cur[dd >> 9], 1);
        bins[pos] = ((unsigned)src[e] << 9) | (unsigned)(dd & 511);
    }
}

// ---- per-bucket: LDS slurp -> hist -> scan -> row[] + in-place exact CSR ----
__global__ __launch_bounds__(256) void k_build(const int* __restrict__ S,
                                               unsigned int* __restrict__ bins,
                                               int* __restrict__ row) {
    __shared__ unsigned int ebuf[BUF_CAP];
    __shared__ int hist[512];
    __shared__ int curs[512];
    __shared__ int lds[256];
    int k = blockIdx.x, t = threadIdx.x;
    int e0 = S[k * NB];
    int e1 = (k == NBKT - 1) ? N_EDGES : S[(k + 1) * NB];
    int cnt = min(e1 - e0, BUF_CAP);
    hist[t] = 0; hist[t + 256] = 0;
    __syncthreads();
    for (int i = t; i < cnt; i += 256) {
        unsigned p = bins[e0 + i];
        ebuf[i] = p;
        atomicAdd(&hist[p & 511u], 1);
    }
    __syncthreads();
    int h0 = hist[2 * t], h1 = hist[2 * t + 1];
    lds[t] = h0 + h1;
    __syncthreads();
    for (int off = 1; off < 256; off <<= 1) {
        int cur = lds[t];
        int add = (t >= off) ? lds[t - off] : 0;
        __syncthreads();
        lds[t] = cur + add;
        __syncthreads();
    }
    int run = e0 + lds[t] - (h0 + h1);
    curs[2 * t] = run;
    curs[2 * t + 1] = run + h0;
    int n0 = k * 512 + 2 * t;
    if (n0 < N_NODES) row[n0] = run;
    if (n0 + 1 < N_NODES) row[n0 + 1] = run + h0;
    if (k == NBKT - 1 && t == 255) row[N_NODES] = N_EDGES;
    __syncthreads();
    for (int i = t; i < cnt; i += 256) {
        unsigned p = ebuf[i];
        int pos = atomicAdd(&curs[p & 511u], 1);
        bins[pos] = p >> 9;
    }
}

// ---- layer 1 aggregate: thread per node ----
__global__ __launch_bounds__(256) void k_agg1(
    const int* __restrict__ row, const unsigned int* __restrict__ csr,
    const float* __restrict__ x, float* __restrict__ agg1) {
    int n = blockIdx.x * 256 + threadIdx.x;
    if (n >= N_NODES) return;
    int r0 = row[n], r1 = row[n + 1];
    float s = 0.0f;
    int j = r0;
    for (; j + 4 <= r1; j += 4) {
        int a0 = (int)csr[j + 0];
        int a1 = (int)csr[j + 1];
        int a2 = (int)csr[j + 2];
        int a3 = (int)csr[j + 3];
        float v0 = x[a0], v1 = x[a1], v2 = x[a2], v3 = x[a3];
        s += (v0 + v1) + (v2 + v3);
    }
    for (; j < r1; ++j) s += x[csr[j]];
    agg1[n] = s / fmaxf((float)(r1 - r0), 1.0f);
}

// ---- layer 1 node update: elementwise -> h1b (bf16) ----
__global__ __launch_bounds__(256) void k_h1(
    const float* __restrict__ agg1, const float* __restrict__ x,
    const float* __restrict__ W1l, const float* __restrict__ b1,
    const float* __restrict__ W1r, unsigned short* __restrict__ h1b) {
    int i = blockIdx.x * 256 + threadIdx.x;
    int n = i >> 6, f = i & 63;
    float v = agg1[n] * W1l[f] + b1[f] + x[n] * W1r[f];
    h1b[i] = f2bf(fmaxf(v, 0.0f));
}

// ---- layer 2 gather: wave = 8 edges x 8 features, uint4 row loads ----
__global__ __launch_bounds__(256) void k_gather2(
    const int* __restrict__ row, const unsigned int* __restrict__ csr,
    const unsigned short* __restrict__ h1b,
    unsigned short* __restrict__ agg2b) {
    int gw = (blockIdx.x * 256 + threadIdx.x) >> 6;
    int L = threadIdx.x & 63;
    int fo = L & 7;        // feature octet: features fo*8 .. fo*8+7
    int es = L >> 3;       // edge slot 0..7
    int nw = gridDim.x * 4;
    for (int n = gw; n < N_NODES; n += nw) {
        int r0 = row[n], r1 = row[n + 1];
        float a0 = 0.f, a1 = 0.f, a2 = 0.f, a3 = 0.f,
              a4 = 0.f, a5 = 0.f, a6 = 0.f, a7 = 0.f;
        int base = r0;
        // main loop: 16 edges / iter, two independent uint4 loads in flight
        for (; base + 16 <= r1; base += 16) {
            int sA = (int)csr[base + es];
            int sB = (int)csr[base + 8 + es];
            uint4 dA = *(const uint4*)(h1b + (size_t)sA * 64 + fo * 8);
            uint4 dB = *(const uint4*)(h1b + (size_t)sB * 64 + fo * 8);
            a0 += lo2f(dA.x); a1 += hi2f(dA.x);
            a2 += lo2f(dA.y); a3 += hi2f(dA.y);
            a4 += lo2f(dA.z); a5 += hi2f(dA.z);
            a6 += lo2f(dA.w); a7 += hi2f(dA.w);
            a0 += lo2f(dB.x); a1 += hi2f(dB.x);
            a2 += lo2f(dB.y); a3 += hi2f(dB.y);
            a4 += lo2f(dB.z); a5 += hi2f(dB.z);
            a6 += lo2f(dB.w); a7 += hi2f(dB.w);
        }
        // masked tail: chunks of 8
        for (; base < r1; base += 8) {
            int e = base + es;
            bool act = e < r1;
            int sA = (int)csr[act ? e : r1 - 1];
            uint4 d = *(const uint4*)(h1b + (size_t)sA * 64 + fo * 8);
            unsigned m = act ? 0xffffffffu : 0u;
            d.x &= m; d.y &= m; d.z &= m; d.w &= m;
            a0 += lo2f(d.x); a1 += hi2f(d.x);
            a2 += lo2f(d.y); a3 += hi2f(d.y);
            a4 += lo2f(d.z); a5 += hi2f(d.z);
            a6 += lo2f(d.w); a7 += hi2f(d.w);
        }
        // butterfly reduce across edge slots (xor bits 3,4,5)
#pragma unroll
        for (int msk = 8; msk <= 32; msk <<= 1) {
            a0 += __shfl_xor(a0, msk, 64);
            a1 += __shfl_xor(a1, msk, 64);
            a2 += __shfl_xor(a2, msk, 64);
            a3 += __shfl_xor(a3, msk, 64);
            a4 += __shfl_xor(a4, msk, 64);
            a5 += __shfl_xor(a5, msk, 64);
            a6 += __shfl_xor(a6, msk, 64);
            a7 += __shfl_xor(a7, msk, 64);
        }
        if (es == 0) {
            float inv = 1.0f / fmaxf((float)(r1 - r0), 1.0f);
            uint4 o;
            o.x = (unsigned)f2bf(a0 * inv) | ((unsigned)f2bf(a1 * inv) << 16);
            o.y = (unsigned)f2bf(a2 * inv) | ((unsigned)f2bf(a3 * inv) << 16);
            o.z = (unsigned)f2bf(a4 * inv) | ((unsigned)f2bf(a5 * inv) << 16);
            o.w = (unsigned)f2bf(a6 * inv) | ((unsigned)f2bf(a7 * inv) << 16);
            *(uint4*)(agg2b + (size_t)n * 64 + fo * 8) = o;
        }
    }
}

// ---- layer 2 GEMM via MFMA: [16 nodes x 128] x [128 x 64] per wave ----
__global__ __launch_bounds__(256) void k_gemv_mfma(
    const unsigned short* __restrict__ agg2b, const unsigned short* __restrict__ h1b,
    const unsigned short* __restrict__ wp, const float* __restrict__ b2,
    unsigned short* __restrict__ h2b) {
    int L = threadIdx.x & 63;
    int wid = threadIdx.x >> 6;
    int n0 = blockIdx.x * 64 + wid * 16;
    if (n0 >= N_NODES) return;
    int m = L & 15, q = L >> 4;
    int nrow = min(n0 + m, N_NODES - 1);

#define LOADB(i) s8v B##i = *(const s8v*)(wp + (i) * 512 + L * 8)
    LOADB(0); LOADB(1); LOADB(2); LOADB(3);
    LOADB(4); LOADB(5); LOADB(6); LOADB(7);
    LOADB(8); LOADB(9); LOADB(10); LOADB(11);
    LOADB(12); LOADB(13); LOADB(14); LOADB(15);
#undef LOADB

    const s8v a0 = *(const s8v*)(agg2b + (size_t)nrow * 64 + q * 8);
    const s8v a1 = *(const s8v*)(agg2b + (size_t)nrow * 64 + 32 + q * 8);
    const s8v a2 = *(const s8v*)(h1b   + (size_t)nrow * 64 + q * 8);
    const s8v a3 = *(const s8v*)(h1b   + (size_t)nrow * 64 + 32 + q * 8);

    f4v acc0 = {0.f, 0.f, 0.f, 0.f}, acc1 = acc0, acc2 = acc0, acc3 = acc0;
    acc0 = __builtin_amdgcn_mfma_f32_16x16x32_bf16(a0, B0,  acc0, 0, 0, 0);
    acc0 = __builtin_amdgcn_mfma_f32_16x16x32_bf16(a1, B4,  acc0, 0, 0, 0);
    acc0 = __builtin_amdgcn_mfma_f32_16x16x32_bf16(a2, B8,  acc0, 0, 0, 0);
    acc0 = __builtin_amdgcn_mfma_f32_16x16x32_bf16(a3, B12, acc0, 0, 0, 0);
    acc1 = __builtin_amdgcn_mfma_f32_16x16x32_bf16(a0, B1,  acc1, 0, 0, 0);
    acc1 = __builtin_amdgcn_mfma_f32_16x16x32_bf16(a1, B5,  acc1, 0, 0, 0);
    acc1 = __builtin_amdgcn_mfma_f32_16x16x32_bf16(a2, B9,  acc1, 0, 0, 0);
    acc1 = __builtin_amdgcn_mfma_f32_16x16x32_bf16(a3, B13, acc1, 0, 0, 0);
    acc2 = __builtin_amdgcn_mfma_f32_16x16x32_bf16(a0, B2,  acc2, 0, 0, 0);
    acc2 = __builtin_amdgcn_mfma_f32_16x16x32_bf16(a1, B6,  acc2, 0, 0, 0);
    acc2 = __builtin_amdgcn_mfma_f32_16x16x32_bf16(a2, B10, acc2, 0, 0, 0);
    acc2 = __builtin_amdgcn_mfma_f32_16x16x32_bf16(a3, B14, acc2, 0, 0, 0);
    acc3 = __builtin_amdgcn_mfma_f32_16x16x32_bf16(a0, B3,  acc3, 0, 0, 0);
    acc3 = __builtin_amdgcn_mfma_f32_16x16x32_bf16(a1, B7,  acc3, 0, 0, 0);
    acc3 = __builtin_amdgcn_mfma_f32_16x16x32_bf16(a2, B11, acc3, 0, 0, 0);
    acc3 = __builtin_amdgcn_mfma_f32_16x16x32_bf16(a3, B15, acc3, 0, 0, 0);

    int fcol = L & 15;
    float bia0 = b2[fcol], bia1 = b2[16 + fcol], bia2 = b2[32 + fcol], bia3 = b2[48 + fcol];
    int rbase = n0 + q * 4;
#pragma unroll
    for (int r = 0; r < 4; r++) {
        int n = rbase + r;
        if (n < N_NODES) {
            size_t o = (size_t)n * 64 + fcol;
            h2b[o]      = f2bf(fmaxf(acc0[r] + bia0, 0.0f));
            h2b[o + 16] = f2bf(fmaxf(acc1[r] + bia1, 0.0f));
            h2b[o + 32] = f2bf(fmaxf(acc2[r] + bia2, 0.0f));
            h2b[o + 48] = f2bf(fmaxf(acc3[r] + bia3, 0.0f));
        }
    }
}

// ---- mean-pool: 4 waves per graph, branch-free strided accumulate ----
__global__ __launch_bounds__(256) void k_pool2(
    const unsigned short* __restrict__ h2b, const int* __restrict__ gstart,
    float* __restrict__ pooled) {
    int w = (blockIdx.x * 256 + threadIdx.x) >> 6;
    int f = threadIdx.x & 63;
    int g = w >> 2;
    int q = w & 3;
    if (g >= N_GRAPHS) return;
    int ns = gstart[g], ne = gstart[g + 1];
    float s = 0.0f;
    int n = ns + q;
    for (; n + 12 < ne; n += 16) {
        float v0 = bf2f(h2b[(size_t)(n)      * 64 + f]);
        float v1 = bf2f(h2b[(size_t)(n + 4)  * 64 + f]);
        float v2 = bf2f(h2b[(size_t)(n + 8)  * 64 + f]);
        float v3 = bf2f(h2b[(size_t)(n + 12) * 64 + f]);
        s += (v0 + v1) + (v2 + v3);
    }
    for (; n < ne; n += 4) s += bf2f(h2b[(size_t)n * 64 + f]);
    atomicAdd(&pooled[g * 64 + f], s / fmaxf((float)(ne - ns), 1.0f));
}

// ---- classifier ----
__global__ void k_cls(const float* __restrict__ pooled, const float* __restrict__ Wc,
                      const float* __restrict__ bc, float* __restrict__ out) {
    __shared__ float rowv[64];
    int g = blockIdx.x;
    int f = threadIdx.x;
    rowv[f] = pooled[g * 64 + f];
    __syncthreads();
    if (f < NCLS) {
        float acc = bc[f];
#pragma unroll
        for (int kk = 0; kk < 64; kk++) acc += rowv[kk] * Wc[kk * NCLS + f];
        out[g * NCLS + f] = acc;
    }
}

extern "C" void kernel_launch(void* const* d_in, const int* in_sizes, int n_in,
                              void* d_out, int out_size, void* d_ws, size_t ws_size,
                              hipStream_t stream) {
    const float* x     = (const float*)d_in[0];
    const int*   eidx  = (const int*)d_in[1];
    const int*   batch = (const int*)d_in[2];
    const float* W1l   = (const float*)d_in[3];
    const float* b1    = (const float*)d_in[4];
    const float* W1r   = (const float*)d_in[5];
    const float* W2l   = (const float*)d_in[6];
    const float* b2    = (const float*)d_in[7];
    const float* W2r   = (const float*)d_in[8];
    const float* Wc    = (const float*)d_in[9];
    const float* bc    = (const float*)d_in[10];
    float* out = (float*)d_out;

    const int* src = eidx;
    const int* dst = eidx + N_EDGES;

    // workspace ≈ 39.9 MB (proven-safe envelope 40.67 MB)
    char* p = (char*)d_ws;
    unsigned int* bins    = (unsigned int*)p;   p += (size_t)N_EDGES * 4;        // 12.8 MB
    unsigned short* h1b   = (unsigned short*)p; p += (size_t)N_NODES * 64 * 2;   // 12.8 MB
    unsigned short* agg2b = (unsigned short*)p; p += (size_t)N_NODES * 64 * 2;   // 12.8 MB
    int* gh    = (int*)p;                       p += (size_t)SCAN_N * 4;         // 0.40 MB
    int* bsum  = (int*)p;                       p += 128 * 4;
    int* row   = (int*)p;                       p += (size_t)(N_NODES + 1) * 4;  // 0.40 MB
    float* agg1= (float*)p;                     p += (size_t)N_NODES * 4;        // 0.40 MB
    int* gstart= (int*)p;                       p += (N_GRAPHS + 1) * 4;
    unsigned short* wp = (unsigned short*)p;    p += 8192 * 2;                   // 16 KB
    // ---- zeroed region ----
    float* pooled = (float*)p;                  p += (size_t)N_GRAPHS * 64 * 4;
    size_t zero_bytes = (size_t)(N_GRAPHS * 64) * 4;

    // h2b aliases bins: bins is dead after k_gather2
    unsigned short* h2b = (unsigned short*)bins;

    hipMemsetAsync(pooled, 0, zero_bytes, stream);

    k_gstart<<<(N_GRAPHS + 256) / 256, 256, 0, stream>>>(batch, gstart);
    k_wprep<<<32, 256, 0, stream>>>(W2l, W2r, wp);
    k_hist <<<NB, 256, 0, stream>>>(dst, gh);
    k_scan1<<<SCAN_NB1, 256, 0, stream>>>(gh, bsum);
    k_scan2<<<1, 64, 0, stream>>>(bsum);
    k_scan3<<<(SCAN_N + 255) / 256, 256, 0, stream>>>(gh, bsum);
    k_bin  <<<NB, 256, 0, stream>>>(src, dst, gh, bins);
    k_build<<<NBKT, 256, 0, stream>>>(gh, bins, row);

    k_agg1     <<<(N_NODES + 255) / 256, 256, 0, stream>>>(row, bins, x, agg1);
    k_h1       <<<(N_NODES * 64) / 256, 256, 0, stream>>>(agg1, x, W1l, b1, W1r, h1b);
    k_gather2  <<<2048, 256, 0, stream>>>(row, bins, h1b, agg2b);
    k_gemv_mfma<<<(N_NODES + 63) / 64, 256, 0, stream>>>(agg2b, h1b, wp, b2, h2b);
    k_pool2    <<<(N_GRAPHS * 4 * 64) / 256, 256, 0, stream>>>(h2b, gstart, pooled);
    k_cls      <<<N_GRAPHS, 64, 0, stream>>>(pooled, Wc, bc, out);
}

// Round 13
// 279.865 us; speedup vs baseline: 1.5613x; 1.0002x over previous
//
#include <hip/hip_runtime.h>

#define N_NODES 100000
#define N_EDGES 3200000
#define N_GRAPHS 1024
#define NCLS 21
#define NBKT 196          // buckets of 512 nodes
#define NB 512            // streaming blocks for hist/bin
#define CHUNK 6250        // N_EDGES / NB
#define SCAN_N (NBKT*NB)  // 100352
#define SCAN_NB1 98       // SCAN_N / 1024
#define BUF_CAP 24576     // 96KB LDS edge buffer

typedef short s8v __attribute__((ext_vector_type(8)));
typedef float f4v __attribute__((ext_vector_type(4)));

__device__ __forceinline__ float bf2f(unsigned short u) {
    return __uint_as_float(((unsigned)u) << 16);
}
__device__ __forceinline__ unsigned short f2bf(float f) {
    unsigned u = __float_as_uint(f);
    unsigned r = 0x7fffu + ((u >> 16) & 1u);   // RNE
    return (unsigned short)((u + r) >> 16);
}
__device__ __forceinline__ float lo2f(unsigned w) { return __uint_as_float(w << 16); }
__device__ __forceinline__ float hi2f(unsigned w) { return __uint_as_float(w & 0xffff0000u); }

// ---- graph start offsets: batch is SORTED -> binary search ----
__global__ void k_gstart(const int* __restrict__ batch, int* __restrict__ gstart) {
    int g = blockIdx.x * 256 + threadIdx.x;
    if (g > N_GRAPHS) return;
    if (g == N_GRAPHS) { gstart[N_GRAPHS] = N_NODES; return; }
    int lo = 0, hi = N_NODES;
    while (lo < hi) { int m = (lo + hi) >> 1; if (batch[m] < g) lo = m + 1; else hi = m; }
    gstart[g] = lo;
}

// ---- pack W2=[W2l;W2r] (128x64) into bf16 B-fragment order ----
__global__ void k_wprep(const float* __restrict__ W2l, const float* __restrict__ W2r,
                        unsigned short* __restrict__ wp) {
    int tid = blockIdx.x * 256 + threadIdx.x;   // 8192 total
    int frag = tid >> 9;
    int r = tid & 511;
    int L = r >> 3, j = r & 7;
    int kstep = frag >> 2, nt = frag & 3;
    int k = kstep * 32 + (L >> 4) * 8 + j;
    int n = nt * 16 + (L & 15);
    float val = (k < 64) ? W2l[k * 64 + n] : W2r[(k - 64) * 64 + n];
    wp[tid] = f2bf(val);
}

// ---- per-block bucket histogram ----
__global__ __launch_bounds__(256) void k_hist(const int* __restrict__ dst,
                                              int* __restrict__ gh) {
    __shared__ int lh[NBKT];
    for (int i = threadIdx.x; i < NBKT; i += 256) lh[i] = 0;
    __syncthreads();
    int e0 = blockIdx.x * CHUNK;
    for (int e = e0 + threadIdx.x; e < e0 + CHUNK; e += 256)
        atomicAdd(&lh[dst[e] >> 9], 1);
    __syncthreads();
    for (int i = threadIdx.x; i < NBKT; i += 256) gh[i * NB + blockIdx.x] = lh[i];
}

// ---- exclusive scan over gh, in place ----
__global__ void k_scan1(int* __restrict__ buf, int* __restrict__ bsum) {
    __shared__ int lds[256];
    int t = threadIdx.x;
    int base = blockIdx.x * 1024 + t * 4;
    int v[4];
#pragma unroll
    for (int i = 0; i < 4; i++) v[i] = buf[base + i];
    int tsum = v[0] + v[1] + v[2] + v[3];
    lds[t] = tsum;
    __syncthreads();
    for (int off = 1; off < 256; off <<= 1) {
        int cur = lds[t];
        int add = (t >= off) ? lds[t - off] : 0;
        __syncthreads();
        lds[t] = cur + add;
        __syncthreads();
    }
    int run = lds[t] - tsum;
#pragma unroll
    for (int i = 0; i < 4; i++) { buf[base + i] = run; run += v[i]; }
    if (t == 255) bsum[blockIdx.x] = lds[255];
}

__global__ void k_scan2(int* __restrict__ bsum) {
    if (threadIdx.x == 0 && blockIdx.x == 0) {
        int acc = 0;
        for (int b = 0; b < SCAN_NB1; b++) { int t = bsum[b]; bsum[b] = acc; acc += t; }
    }
}

__global__ void k_scan3(int* __restrict__ buf, const int* __restrict__ bsum) {
    int i = blockIdx.x * 256 + threadIdx.x;
    if (i < SCAN_N) buf[i] += bsum[i >> 10];
}

// ---- bin edges into bucket-grouped runs ----
__global__ __launch_bounds__(256) void k_bin(const int* __restrict__ src,
                                             const int* __restrict__ dst,
                                             const int* __restrict__ S,
                                             unsigned int* __restrict__ bins) {
    __shared__ int cur[NBKT];
    for (int i = threadIdx.x; i < NBKT; i += 256) cur[i] = S[i * NB + blockIdx.x];
    __syncthreads();
    int e0 = blockIdx.x * CHUNK;
    for (int e = e0 + threadIdx.x; e < e0 + CHUNK; e += 256) {
        int dd = dst[e];
        int pos = atomicAdd(&cur[dd >> 9], 1);
        bins[pos] = ((unsigned)src[e] << 9) | (unsigned)(dd & 511);
    }
}

// ---- per-bucket: LDS slurp -> hist -> scan -> row[] + in-place exact CSR ----
__global__ __launch_bounds__(256) void k_build(const int* __restrict__ S,
                                               unsigned int* __restrict__ bins,
                                               int* __restrict__ row) {
    __shared__ unsigned int ebuf[BUF_CAP];
    __shared__ int hist[512];
    __shared__ int curs[512];
    __shared__ int lds[256];
    int k = blockIdx.x, t = threadIdx.x;
    int e0 = S[k * NB];
    int e1 = (k == NBKT - 1) ? N_EDGES : S[(k + 1) * NB];
    int cnt = min(e1 - e0, BUF_CAP);
    hist[t] = 0; hist[t + 256] = 0;
    __syncthreads();
    for (int i = t; i < cnt; i += 256) {
        unsigned p = bins[e0 + i];
        ebuf[i] = p;
        atomicAdd(&hist[p & 511u], 1);
    }
    __syncthreads();
    int h0 = hist[2 * t], h1 = hist[2 * t + 1];
    lds[t] = h0 + h1;
    __syncthreads();
    for (int off = 1; off < 256; off <<= 1) {
        int cur = lds[t];
        int add = (t >= off) ? lds[t - off] : 0;
        __syncthreads();
        lds[t] = cur + add;
        __syncthreads();
    }
    int run = e0 + lds[t] - (h0 + h1);
    curs[2 * t] = run;
    curs[2 * t + 1] = run + h0;
    int n0 = k * 512 + 2 * t;
    if (n0 < N_NODES) row[n0] = run;
    if (n0 + 1 < N_NODES) row[n0 + 1] = run + h0;
    if (k == NBKT - 1 && t == 255) row[N_NODES] = N_EDGES;
    __syncthreads();
    for (int i = t; i < cnt; i += 256) {
        unsigned p = ebuf[i];
        int pos = atomicAdd(&curs[p & 511u], 1);
        bins[pos] = p >> 9;
    }
}

// ---- layer 1 aggregate: thread per node ----
__global__ __launch_bounds__(256) void k_agg1(
    const int* __restrict__ row, const unsigned int* __restrict__ csr,
    const float* __restrict__ x, float* __restrict__ agg1) {
    int n = blockIdx.x * 256 + threadIdx.x;
    if (n >= N_NODES) return;
    int r0 = row[n], r1 = row[n + 1];
    float s = 0.0f;
    int j = r0;
    for (; j + 4 <= r1; j += 4) {
        int a0 = (int)csr[j + 0];
        int a1 = (int)csr[j + 1];
        int a2 = (int)csr[j + 2];
        int a3 = (int)csr[j + 3];
        float v0 = x[a0], v1 = x[a1], v2 = x[a2], v3 = x[a3];
        s += (v0 + v1) + (v2 + v3);
    }
    for (; j < r1; ++j) s += x[csr[j]];
    agg1[n] = s / fmaxf((float)(r1 - r0), 1.0f);
}

// ---- layer 1 node update: elementwise -> h1b (bf16) ----
__global__ __launch_bounds__(256) void k_h1(
    const float* __restrict__ agg1, const float* __restrict__ x,
    const float* __restrict__ W1l, const float* __restrict__ b1,
    const float* __restrict__ W1r, unsigned short* __restrict__ h1b) {
    int i = blockIdx.x * 256 + threadIdx.x;
    int n = i >> 6, f = i & 63;
    float v = agg1[n] * W1l[f] + b1[f] + x[n] * W1r[f];
    h1b[i] = f2bf(fmaxf(v, 0.0f));
}

// ---- layer 2 gather: 8 edges x 8 features, 32-edge unroll,
//      7-shfl reduce-scatter (each lane ends owning feature fo*8+es) ----
__global__ __launch_bounds__(256) void k_gather2(
    const int* __restrict__ row, const unsigned int* __restrict__ csr,
    const unsigned short* __restrict__ h1b,
    unsigned short* __restrict__ agg2b) {
    int gw = (blockIdx.x * 256 + threadIdx.x) >> 6;
    int L = threadIdx.x & 63;
    int fo = L & 7;        // feature octet
    int es = L >> 3;       // edge slot 0..7
    int nw = gridDim.x * 4;
    for (int n = gw; n < N_NODES; n += nw) {
        int r0 = row[n], r1 = row[n + 1];
        float a0 = 0.f, a1 = 0.f, a2 = 0.f, a3 = 0.f,
              a4 = 0.f, a5 = 0.f, a6 = 0.f, a7 = 0.f;
        int base = r0;
        // 32 edges / iter: 4 independent uint4 loads in flight
        for (; base + 32 <= r1; base += 32) {
            int sA = (int)csr[base + es];
            int sB = (int)csr[base + 8 + es];
            int sC = (int)csr[base + 16 + es];
            int sD = (int)csr[base + 24 + es];
            uint4 dA = *(const uint4*)(h1b + (size_t)sA * 64 + fo * 8);
            uint4 dB = *(const uint4*)(h1b + (size_t)sB * 64 + fo * 8);
            uint4 dC = *(const uint4*)(h1b + (size_t)sC * 64 + fo * 8);
            uint4 dD = *(const uint4*)(h1b + (size_t)sD * 64 + fo * 8);
            a0 += lo2f(dA.x); a1 += hi2f(dA.x); a2 += lo2f(dA.y); a3 += hi2f(dA.y);
            a4 += lo2f(dA.z); a5 += hi2f(dA.z); a6 += lo2f(dA.w); a7 += hi2f(dA.w);
            a0 += lo2f(dB.x); a1 += hi2f(dB.x); a2 += lo2f(dB.y); a3 += hi2f(dB.y);
            a4 += lo2f(dB.z); a5 += hi2f(dB.z); a6 += lo2f(dB.w); a7 += hi2f(dB.w);
            a0 += lo2f(dC.x); a1 += hi2f(dC.x); a2 += lo2f(dC.y); a3 += hi2f(dC.y);
            a4 += lo2f(dC.z); a5 += hi2f(dC.z); a6 += lo2f(dC.w); a7 += hi2f(dC.w);
            a0 += lo2f(dD.x); a1 += hi2f(dD.x); a2 += lo2f(dD.y); a3 += hi2f(dD.y);
            a4 += lo2f(dD.z); a5 += hi2f(dD.z); a6 += lo2f(dD.w); a7 += hi2f(dD.w);
        }
        for (; base + 16 <= r1; base += 16) {
            int sA = (int)csr[base + es];
            int sB = (int)csr[base + 8 + es];
            uint4 dA = *(const uint4*)(h1b + (size_t)sA * 64 + fo * 8);
            uint4 dB = *(const uint4*)(h1b + (size_t)sB * 64 + fo * 8);
            a0 += lo2f(dA.x); a1 += hi2f(dA.x); a2 += lo2f(dA.y); a3 += hi2f(dA.y);
            a4 += lo2f(dA.z); a5 += hi2f(dA.z); a6 += lo2f(dA.w); a7 += hi2f(dA.w);
            a0 += lo2f(dB.x); a1 += hi2f(dB.x); a2 += lo2f(dB.y); a3 += hi2f(dB.y);
            a4 += lo2f(dB.z); a5 += hi2f(dB.z); a6 += lo2f(dB.w); a7 += hi2f(dB.w);
        }
        for (; base < r1; base += 8) {   // masked tail, 8 edges
            int e = base + es;
            bool act = e < r1;
            int sA = (int)csr[act ? e : r1 - 1];
            uint4 d = *(const uint4*)(h1b + (size_t)sA * 64 + fo * 8);
            unsigned m = act ? 0xffffffffu : 0u;
            d.x &= m; d.y &= m; d.z &= m; d.w &= m;
            a0 += lo2f(d.x); a1 += hi2f(d.x); a2 += lo2f(d.y); a3 += hi2f(d.y);
            a4 += lo2f(d.z); a5 += hi2f(d.z); a6 += lo2f(d.w); a7 += hi2f(d.w);
        }
        // reduce-scatter across edge slots: 7 shfls total.
        // round 1 (xor 32, es bit2): keep high half if bit set
        {
            bool hi = (es & 4) != 0;
            float s0 = hi ? a0 : a4, s1 = hi ? a1 : a5, s2 = hi ? a2 : a6, s3 = hi ? a3 : a7;
            float r0v = __shfl_xor(s0, 32, 64);
            float r1v = __shfl_xor(s1, 32, 64);
            float r2v = __shfl_xor(s2, 32, 64);
            float r3v = __shfl_xor(s3, 32, 64);
            a0 = (hi ? a4 : a0) + r0v;
            a1 = (hi ? a5 : a1) + r1v;
            a2 = (hi ? a6 : a2) + r2v;
            a3 = (hi ? a7 : a3) + r3v;
        }
        // round 2 (xor 16, es bit1)
        {
            bool hi = (es & 2) != 0;
            float s0 = hi ? a0 : a2, s1 = hi ? a1 : a3;
            float r0v = __shfl_xor(s0, 16, 64);
            float r1v = __shfl_xor(s1, 16, 64);
            a0 = (hi ? a2 : a0) + r0v;
            a1 = (hi ? a3 : a1) + r1v;
        }
        // round 3 (xor 8, es bit0)
        {
            bool hi = (es & 1) != 0;
            float s0 = hi ? a0 : a1;
            float r0v = __shfl_xor(s0, 8, 64);
            a0 = (hi ? a1 : a0) + r0v;
        }
        // lane owns feature fo*8 + es (bit2,bit1,bit0 of sub-index = es bits)
        float inv = 1.0f / fmaxf((float)(r1 - r0), 1.0f);
        agg2b[(size_t)n * 64 + fo * 8 + es] = f2bf(a0 * inv);
    }
}

// ---- layer 2 GEMM via MFMA: [16 nodes x 128] x [128 x 64] per wave ----
__global__ __launch_bounds__(256) void k_gemv_mfma(
    const unsigned short* __restrict__ agg2b, const unsigned short* __restrict__ h1b,
    const unsigned short* __restrict__ wp, const float* __restrict__ b2,
    unsigned short* __restrict__ h2b) {
    int L = threadIdx.x & 63;
    int wid = threadIdx.x >> 6;
    int n0 = blockIdx.x * 64 + wid * 16;
    if (n0 >= N_NODES) return;
    int m = L & 15, q = L >> 4;
    int nrow = min(n0 + m, N_NODES - 1);

#define LOADB(i) s8v B##i = *(const s8v*)(wp + (i) * 512 + L * 8)
    LOADB(0); LOADB(1); LOADB(2); LOADB(3);
    LOADB(4); LOADB(5); LOADB(6); LOADB(7);
    LOADB(8); LOADB(9); LOADB(10); LOADB(11);
    LOADB(12); LOADB(13); LOADB(14); LOADB(15);
#undef LOADB

    const s8v a0 = *(const s8v*)(agg2b + (size_t)nrow * 64 + q * 8);
    const s8v a1 = *(const s8v*)(agg2b + (size_t)nrow * 64 + 32 + q * 8);
    const s8v a2 = *(const s8v*)(h1b   + (size_t)nrow * 64 + q * 8);
    const s8v a3 = *(const s8v*)(h1b   + (size_t)nrow * 64 + 32 + q * 8);

    f4v acc0 = {0.f, 0.f, 0.f, 0.f}, acc1 = acc0, acc2 = acc0, acc3 = acc0;
    acc0 = __builtin_amdgcn_mfma_f32_16x16x32_bf16(a0, B0,  acc0, 0, 0, 0);
    acc0 = __builtin_amdgcn_mfma_f32_16x16x32_bf16(a1, B4,  acc0, 0, 0, 0);
    acc0 = __builtin_amdgcn_mfma_f32_16x16x32_bf16(a2, B8,  acc0, 0, 0, 0);
    acc0 = __builtin_amdgcn_mfma_f32_16x16x32_bf16(a3, B12, acc0, 0, 0, 0);
    acc1 = __builtin_amdgcn_mfma_f32_16x16x32_bf16(a0, B1,  acc1, 0, 0, 0);
    acc1 = __builtin_amdgcn_mfma_f32_16x16x32_bf16(a1, B5,  acc1, 0, 0, 0);
    acc1 = __builtin_amdgcn_mfma_f32_16x16x32_bf16(a2, B9,  acc1, 0, 0, 0);
    acc1 = __builtin_amdgcn_mfma_f32_16x16x32_bf16(a3, B13, acc1, 0, 0, 0);
    acc2 = __builtin_amdgcn_mfma_f32_16x16x32_bf16(a0, B2,  acc2, 0, 0, 0);
    acc2 = __builtin_amdgcn_mfma_f32_16x16x32_bf16(a1, B6,  acc2, 0, 0, 0);
    acc2 = __builtin_amdgcn_mfma_f32_16x16x32_bf16(a2, B10, acc2, 0, 0, 0);
    acc2 = __builtin_amdgcn_mfma_f32_16x16x32_bf16(a3, B14, acc2, 0, 0, 0);
    acc3 = __builtin_amdgcn_mfma_f32_16x16x32_bf16(a0, B3,  acc3, 0, 0, 0);
    acc3 = __builtin_amdgcn_mfma_f32_16x16x32_bf16(a1, B7,  acc3, 0, 0, 0);
    acc3 = __builtin_amdgcn_mfma_f32_16x16x32_bf16(a2, B11, acc3, 0, 0, 0);
    acc3 = __builtin_amdgcn_mfma_f32_16x16x32_bf16(a3, B15, acc3, 0, 0, 0);

    int fcol = L & 15;
    float bia0 = b2[fcol], bia1 = b2[16 + fcol], bia2 = b2[32 + fcol], bia3 = b2[48 + fcol];
    int rbase = n0 + q * 4;
#pragma unroll
    for (int r = 0; r < 4; r++) {
        int n = rbase + r;
        if (n < N_NODES) {
            size_t o = (size_t)n * 64 + fcol;
            h2b[o]      = f2bf(fmaxf(acc0[r] + bia0, 0.0f));
            h2b[o + 16] = f2bf(fmaxf(acc1[r] + bia1, 0.0f));
            h2b[o + 32] = f2bf(fmaxf(acc2[r] + bia2, 0.0f));
            h2b[o + 48] = f2bf(fmaxf(acc3[r] + bia3, 0.0f));
        }
    }
}

// ---- mean-pool: 4 waves per graph, branch-free strided accumulate ----
__global__ __launch_bounds__(256) void k_pool2(
    const unsigned short* __restrict__ h2b, const int* __restrict__ gstart,
    float* __restrict__ pooled) {
    int w = (blockIdx.x * 256 + threadIdx.x) >> 6;
    int f = threadIdx.x & 63;
    int g = w >> 2;
    int q = w & 3;
    if (g >= N_GRAPHS) return;
    int ns = gstart[g], ne = gstart[g + 1];
    float s = 0.0f;
    int n = ns + q;
    for (; n + 12 < ne; n += 16) {
        float v0 = bf2f(h2b[(size_t)(n)      * 64 + f]);
        float v1 = bf2f(h2b[(size_t)(n + 4)  * 64 + f]);
        float v2 = bf2f(h2b[(size_t)(n + 8)  * 64 + f]);
        float v3 = bf2f(h2b[(size_t)(n + 12) * 64 + f]);
        s += (v0 + v1) + (v2 + v3);
    }
    for (; n < ne; n += 4) s += bf2f(h2b[(size_t)n * 64 + f]);
    atomicAdd(&pooled[g * 64 + f], s / fmaxf((float)(ne - ns), 1.0f));
}

// ---- classifier ----
__global__ void k_cls(const float* __restrict__ pooled, const float* __restrict__ Wc,
                      const float* __restrict__ bc, float* __restrict__ out) {
    __shared__ float rowv[64];
    int g = blockIdx.x;
    int f = threadIdx.x;
    rowv[f] = pooled[g * 64 + f];
    __syncthreads();
    if (f < NCLS) {
        float acc = bc[f];
#pragma unroll
        for (int kk = 0; kk < 64; kk++) acc += rowv[kk] * Wc[kk * NCLS + f];
        out[g * NCLS + f] = acc;
    }
}

extern "C" void kernel_launch(void* const* d_in, const int* in_sizes, int n_in,
                              void* d_out, int out_size, void* d_ws, size_t ws_size,
                              hipStream_t stream) {
    const float* x     = (const float*)d_in[0];
    const int*   eidx  = (const int*)d_in[1];
    const int*   batch = (const int*)d_in[2];
    const float* W1l   = (const float*)d_in[3];
    const float* b1    = (const float*)d_in[4];
    const float* W1r   = (const float*)d_in[5];
    const float* W2l   = (const float*)d_in[6];
    const float* b2    = (const float*)d_in[7];
    const float* W2r   = (const float*)d_in[8];
    const float* Wc    = (const float*)d_in[9];
    const float* bc    = (const float*)d_in[10];
    float* out = (float*)d_out;

    const int* src = eidx;
    const int* dst = eidx + N_EDGES;

    // workspace ≈ 39.9 MB (proven-safe envelope 40.67 MB)
    char* p = (char*)d_ws;
    unsigned int* bins    = (unsigned int*)p;   p += (size_t)N_EDGES * 4;        // 12.8 MB
    unsigned short* h1b   = (unsigned short*)p; p += (size_t)N_NODES * 64 * 2;   // 12.8 MB
    unsigned short* agg2b = (unsigned short*)p; p += (size_t)N_NODES * 64 * 2;   // 12.8 MB
    int* gh    = (int*)p;                       p += (size_t)SCAN_N * 4;         // 0.40 MB
    int* bsum  = (int*)p;                       p += 128 * 4;
    int* row   = (int*)p;                       p += (size_t)(N_NODES + 1) * 4;  // 0.40 MB
    float* agg1= (float*)p;                     p += (size_t)N_NODES * 4;        // 0.40 MB
    int* gstart= (int*)p;                       p += (N_GRAPHS + 1) * 4;
    unsigned short* wp = (unsigned short*)p;    p += 8192 * 2;                   // 16 KB
    // ---- zeroed region ----
    float* pooled = (float*)p;                  p += (size_t)N_GRAPHS * 64 * 4;
    size_t zero_bytes = (size_t)(N_GRAPHS * 64) * 4;

    // h2b aliases bins: bins is dead after k_gather2
    unsigned short* h2b = (unsigned short*)bins;

    hipMemsetAsync(pooled, 0, zero_bytes, stream);

    k_gstart<<<(N_GRAPHS + 256) / 256, 256, 0, stream>>>(batch, gstart);
    k_wprep<<<32, 256, 0, stream>>>(W2l, W2r, wp);
    k_hist <<<NB, 256, 0, stream>>>(dst, gh);
    k_scan1<<<SCAN_NB1, 256, 0, stream>>>(gh, bsum);
    k_scan2<<<1, 64, 0, stream>>>(bsum);
    k_scan3<<<(SCAN_N + 255) / 256, 256, 0, stream>>>(gh, bsum);
    k_bin  <<<NB, 256, 0, stream>>>(src, dst, gh, bins);
    k_build<<<NBKT, 256, 0, stream>>>(gh, bins, row);

    k_agg1     <<<(N_NODES + 255) / 256, 256, 0, stream>>>(row, bins, x, agg1);
    k_h1       <<<(N_NODES * 64) / 256, 256, 0, stream>>>(agg1, x, W1l, b1, W1r, h1b);
    k_gather2  <<<2048, 256, 0, stream>>>(row, bins, h1b, agg2b);
    k_gemv_mfma<<<(N_NODES + 63) / 64, 256, 0, stream>>>(agg2b, h1b, wp, b2, h2b);
    k_pool2    <<<(N_GRAPHS * 4 * 64) / 256, 256, 0, stream>>>(h2b, gstart, pooled);
    k_cls      <<<N_GRAPHS, 64, 0, stream>>>(pooled, Wc, bc, out);
}

// Round 14
// 269.060 us; speedup vs baseline: 1.6240x; 1.0402x over previous
//
#include <hip/hip_runtime.h>

#define N_NODES 100000
#define N_EDGES 3200000
#define N_GRAPHS 1024
#define NCLS 21
#define NBKT 196          // buckets of 512 nodes
#define NB 512            // streaming blocks for hist/bin
#define CHUNK 6250        // N_EDGES / NB
#define SCAN_N (NBKT*NB)  // 100352
#define SCAN_NB1 98       // SCAN_N / 1024
#define BUF_CAP 24576     // 96KB LDS edge buffer

typedef short s8v __attribute__((ext_vector_type(8)));
typedef float f4v __attribute__((ext_vector_type(4)));

__device__ __forceinline__ float bf2f(unsigned short u) {
    return __uint_as_float(((unsigned)u) << 16);
}
__device__ __forceinline__ unsigned short f2bf(float f) {
    unsigned u = __float_as_uint(f);
    unsigned r = 0x7fffu + ((u >> 16) & 1u);   // RNE
    return (unsigned short)((u + r) >> 16);
}
__device__ __forceinline__ float lo2f(unsigned w) { return __uint_as_float(w << 16); }
__device__ __forceinline__ float hi2f(unsigned w) { return __uint_as_float(w & 0xffff0000u); }

// ---- fused prep: blocks 0..31 pack W2 B-fragments, blocks 32..36 gstart ----
__global__ void k_prep(const float* __restrict__ W2l, const float* __restrict__ W2r,
                       unsigned short* __restrict__ wp,
                       const int* __restrict__ batch, int* __restrict__ gstart) {
    if (blockIdx.x < 32) {
        int tid = blockIdx.x * 256 + threadIdx.x;   // 8192 total
        int frag = tid >> 9;
        int r = tid & 511;
        int L = r >> 3, j = r & 7;
        int kstep = frag >> 2, nt = frag & 3;
        int k = kstep * 32 + (L >> 4) * 8 + j;
        int n = nt * 16 + (L & 15);
        float val = (k < 64) ? W2l[k * 64 + n] : W2r[(k - 64) * 64 + n];
        wp[tid] = f2bf(val);
    } else {
        int g = (blockIdx.x - 32) * 256 + threadIdx.x;
        if (g > N_GRAPHS) return;
        if (g == N_GRAPHS) { gstart[N_GRAPHS] = N_NODES; return; }
        int lo = 0, hi = N_NODES;
        while (lo < hi) { int m = (lo + hi) >> 1; if (batch[m] < g) lo = m + 1; else hi = m; }
        gstart[g] = lo;
    }
}

// ---- per-block bucket histogram (int2 streaming reads) ----
__global__ __launch_bounds__(256) void k_hist(const int* __restrict__ dst,
                                              int* __restrict__ gh) {
    __shared__ int lh[NBKT];
    for (int i = threadIdx.x; i < NBKT; i += 256) lh[i] = 0;
    __syncthreads();
    const int2* d2 = (const int2*)(dst + blockIdx.x * CHUNK);
    for (int i = threadIdx.x; i < CHUNK / 2; i += 256) {
        int2 d = d2[i];
        atomicAdd(&lh[d.x >> 9], 1);
        atomicAdd(&lh[d.y >> 9], 1);
    }
    __syncthreads();
    for (int i = threadIdx.x; i < NBKT; i += 256) gh[i * NB + blockIdx.x] = lh[i];
}

// ---- scan 1: per-1024-chunk exclusive scan in place + block sums ----
__global__ void k_scan1(int* __restrict__ buf, int* __restrict__ bsum) {
    __shared__ int lds[256];
    int t = threadIdx.x;
    int base = blockIdx.x * 1024 + t * 4;
    int v[4];
#pragma unroll
    for (int i = 0; i < 4; i++) v[i] = buf[base + i];
    int tsum = v[0] + v[1] + v[2] + v[3];
    lds[t] = tsum;
    __syncthreads();
    for (int off = 1; off < 256; off <<= 1) {
        int cur = lds[t];
        int add = (t >= off) ? lds[t - off] : 0;
        __syncthreads();
        lds[t] = cur + add;
        __syncthreads();
    }
    int run = lds[t] - tsum;
#pragma unroll
    for (int i = 0; i < 4; i++) { buf[base + i] = run; run += v[i]; }
    if (t == 255) bsum[blockIdx.x] = lds[255];
}

// ---- scan 2: serial exclusive scan of 98 block sums ----
__global__ void k_scan2(int* __restrict__ bsum) {
    if (threadIdx.x == 0 && blockIdx.x == 0) {
        int acc = 0;
        for (int b = 0; b < SCAN_NB1; b++) { int t = bsum[b]; bsum[b] = acc; acc += t; }
    }
}

// ---- bin edges (int2 reads; bsum folded inline — no scan3 pass) ----
__global__ __launch_bounds__(256) void k_bin(const int* __restrict__ src,
                                             const int* __restrict__ dst,
                                             const int* __restrict__ S,
                                             const int* __restrict__ bsum,
                                             unsigned int* __restrict__ bins) {
    __shared__ int cur[NBKT];
    for (int i = threadIdx.x; i < NBKT; i += 256) {
        int idx = i * NB + blockIdx.x;
        cur[i] = S[idx] + bsum[idx >> 10];
    }
    __syncthreads();
    const int2* s2 = (const int2*)(src + blockIdx.x * CHUNK);
    const int2* d2 = (const int2*)(dst + blockIdx.x * CHUNK);
    for (int i = threadIdx.x; i < CHUNK / 2; i += 256) {
        int2 s = s2[i];
        int2 d = d2[i];
        int p0 = atomicAdd(&cur[d.x >> 9], 1);
        bins[p0] = ((unsigned)s.x << 9) | (unsigned)(d.x & 511);
        int p1 = atomicAdd(&cur[d.y >> 9], 1);
        bins[p1] = ((unsigned)s.y << 9) | (unsigned)(d.y & 511);
    }
}

// ---- per-bucket: LDS slurp -> hist -> scan -> row[] + in-place exact CSR ----
__global__ __launch_bounds__(256) void k_build(const int* __restrict__ S,
                                               const int* __restrict__ bsum,
                                               unsigned int* __restrict__ bins,
                                               int* __restrict__ row) {
    __shared__ unsigned int ebuf[BUF_CAP];
    __shared__ int hist[512];
    __shared__ int curs[512];
    __shared__ int lds[256];
    int k = blockIdx.x, t = threadIdx.x;
    int i0 = k * NB;
    int e0 = S[i0] + bsum[i0 >> 10];
    int e1;
    if (k == NBKT - 1) e1 = N_EDGES;
    else { int i1 = (k + 1) * NB; e1 = S[i1] + bsum[i1 >> 10]; }
    int cnt = min(e1 - e0, BUF_CAP);
    hist[t] = 0; hist[t + 256] = 0;
    __syncthreads();
    for (int i = t; i < cnt; i += 256) {
        unsigned p = bins[e0 + i];
        ebuf[i] = p;
        atomicAdd(&hist[p & 511u], 1);
    }
    __syncthreads();
    int h0 = hist[2 * t], h1 = hist[2 * t + 1];
    lds[t] = h0 + h1;
    __syncthreads();
    for (int off = 1; off < 256; off <<= 1) {
        int cur = lds[t];
        int add = (t >= off) ? lds[t - off] : 0;
        __syncthreads();
        lds[t] = cur + add;
        __syncthreads();
    }
    int run = e0 + lds[t] - (h0 + h1);
    curs[2 * t] = run;
    curs[2 * t + 1] = run + h0;
    int n0 = k * 512 + 2 * t;
    if (n0 < N_NODES) row[n0] = run;
    if (n0 + 1 < N_NODES) row[n0 + 1] = run + h0;
    if (k == NBKT - 1 && t == 255) row[N_NODES] = N_EDGES;
    __syncthreads();
    for (int i = t; i < cnt; i += 256) {
        unsigned p = ebuf[i];
        int pos = atomicAdd(&curs[p & 511u], 1);
        bins[pos] = p >> 9;
    }
}

// ---- layer 1 fused: per-node gather (thread/node) + elementwise -> h1b ----
__global__ __launch_bounds__(256) void k_l1f(
    const int* __restrict__ row, const unsigned int* __restrict__ csr,
    const float* __restrict__ x,
    const float* __restrict__ W1l, const float* __restrict__ b1,
    const float* __restrict__ W1r, unsigned short* __restrict__ h1b) {
    __shared__ float aggv[256];
    int n0 = blockIdx.x * 256;
    int n = n0 + threadIdx.x;
    if (n < N_NODES) {
        int r0 = row[n], r1 = row[n + 1];
        float s = 0.0f;
        int j = r0;
        for (; j + 4 <= r1; j += 4) {
            int a0 = (int)csr[j + 0];
            int a1 = (int)csr[j + 1];
            int a2 = (int)csr[j + 2];
            int a3 = (int)csr[j + 3];
            float v0 = x[a0], v1 = x[a1], v2 = x[a2], v3 = x[a3];
            s += (v0 + v1) + (v2 + v3);
        }
        for (; j < r1; ++j) s += x[csr[j]];
        aggv[threadIdx.x] = s / fmaxf((float)(r1 - r0), 1.0f);
    }
    __syncthreads();
    int lim = min(256, N_NODES - n0) * 64;
    for (int i = threadIdx.x; i < lim; i += 256) {
        int slot = i >> 6, f = i & 63;
        int nn = n0 + slot;
        float v = aggv[slot] * W1l[f] + b1[f] + x[nn] * W1r[f];
        h1b[(size_t)nn * 64 + f] = f2bf(fmaxf(v, 0.0f));
    }
}

// ---- layer 2 gather: 8 edges x 8 features, 32-edge unroll, 7-shfl reduce-scatter ----
__global__ __launch_bounds__(256) void k_gather2(
    const int* __restrict__ row, const unsigned int* __restrict__ csr,
    const unsigned short* __restrict__ h1b,
    unsigned short* __restrict__ agg2b) {
    int gw = (blockIdx.x * 256 + threadIdx.x) >> 6;
    int L = threadIdx.x & 63;
    int fo = L & 7;
    int es = L >> 3;
    int nw = gridDim.x * 4;
    for (int n = gw; n < N_NODES; n += nw) {
        int r0 = row[n], r1 = row[n + 1];
        float a0 = 0.f, a1 = 0.f, a2 = 0.f, a3 = 0.f,
              a4 = 0.f, a5 = 0.f, a6 = 0.f, a7 = 0.f;
        int base = r0;
        for (; base + 32 <= r1; base += 32) {
            int sA = (int)csr[base + es];
            int sB = (int)csr[base + 8 + es];
            int sC = (int)csr[base + 16 + es];
            int sD = (int)csr[base + 24 + es];
            uint4 dA = *(const uint4*)(h1b + (size_t)sA * 64 + fo * 8);
            uint4 dB = *(const uint4*)(h1b + (size_t)sB * 64 + fo * 8);
            uint4 dC = *(const uint4*)(h1b + (size_t)sC * 64 + fo * 8);
            uint4 dD = *(const uint4*)(h1b + (size_t)sD * 64 + fo * 8);
            a0 += lo2f(dA.x); a1 += hi2f(dA.x); a2 += lo2f(dA.y); a3 += hi2f(dA.y);
            a4 += lo2f(dA.z); a5 += hi2f(dA.z); a6 += lo2f(dA.w); a7 += hi2f(dA.w);
            a0 += lo2f(dB.x); a1 += hi2f(dB.x); a2 += lo2f(dB.y); a3 += hi2f(dB.y);
            a4 += lo2f(dB.z); a5 += hi2f(dB.z); a6 += lo2f(dB.w); a7 += hi2f(dB.w);
            a0 += lo2f(dC.x); a1 += hi2f(dC.x); a2 += lo2f(dC.y); a3 += hi2f(dC.y);
            a4 += lo2f(dC.z); a5 += hi2f(dC.z); a6 += lo2f(dC.w); a7 += hi2f(dC.w);
            a0 += lo2f(dD.x); a1 += hi2f(dD.x); a2 += lo2f(dD.y); a3 += hi2f(dD.y);
            a4 += lo2f(dD.z); a5 += hi2f(dD.z); a6 += lo2f(dD.w); a7 += hi2f(dD.w);
        }
        for (; base + 16 <= r1; base += 16) {
            int sA = (int)csr[base + es];
            int sB = (int)csr[base + 8 + es];
            uint4 dA = *(const uint4*)(h1b + (size_t)sA * 64 + fo * 8);
            uint4 dB = *(const uint4*)(h1b + (size_t)sB * 64 + fo * 8);
            a0 += lo2f(dA.x); a1 += hi2f(dA.x); a2 += lo2f(dA.y); a3 += hi2f(dA.y);
            a4 += lo2f(dA.z); a5 += hi2f(dA.z); a6 += lo2f(dA.w); a7 += hi2f(dA.w);
            a0 += lo2f(dB.x); a1 += hi2f(dB.x); a2 += lo2f(dB.y); a3 += hi2f(dB.y);
            a4 += lo2f(dB.z); a5 += hi2f(dB.z); a6 += lo2f(dB.w); a7 += hi2f(dB.w);
        }
        for (; base < r1; base += 8) {
            int e = base + es;
            bool act = e < r1;
            int sA = (int)csr[act ? e : r1 - 1];
            uint4 d = *(const uint4*)(h1b + (size_t)sA * 64 + fo * 8);
            unsigned m = act ? 0xffffffffu : 0u;
            d.x &= m; d.y &= m; d.z &= m; d.w &= m;
            a0 += lo2f(d.x); a1 += hi2f(d.x); a2 += lo2f(d.y); a3 += hi2f(d.y);
            a4 += lo2f(d.z); a5 += hi2f(d.z); a6 += lo2f(d.w); a7 += hi2f(d.w);
        }
        {
            bool hi = (es & 4) != 0;
            float s0 = hi ? a0 : a4, s1 = hi ? a1 : a5, s2 = hi ? a2 : a6, s3 = hi ? a3 : a7;
            float r0v = __shfl_xor(s0, 32, 64);
            float r1v = __shfl_xor(s1, 32, 64);
            float r2v = __shfl_xor(s2, 32, 64);
            float r3v = __shfl_xor(s3, 32, 64);
            a0 = (hi ? a4 : a0) + r0v;
            a1 = (hi ? a5 : a1) + r1v;
            a2 = (hi ? a6 : a2) + r2v;
            a3 = (hi ? a7 : a3) + r3v;
        }
        {
            bool hi = (es & 2) != 0;
            float s0 = hi ? a0 : a2, s1 = hi ? a1 : a3;
            float r0v = __shfl_xor(s0, 16, 64);
            float r1v = __shfl_xor(s1, 16, 64);
            a0 = (hi ? a2 : a0) + r0v;
            a1 = (hi ? a3 : a1) + r1v;
        }
        {
            bool hi = (es & 1) != 0;
            float s0 = hi ? a0 : a1;
            float r0v = __shfl_xor(s0, 8, 64);
            a0 = (hi ? a1 : a0) + r0v;
        }
        float inv = 1.0f / fmaxf((float)(r1 - r0), 1.0f);
        agg2b[(size_t)n * 64 + fo * 8 + es] = f2bf(a0 * inv);
    }
}

// ---- layer 2 GEMM via MFMA: [16 nodes x 128] x [128 x 64] per wave ----
__global__ __launch_bounds__(256) void k_gemv_mfma(
    const unsigned short* __restrict__ agg2b, const unsigned short* __restrict__ h1b,
    const unsigned short* __restrict__ wp, const float* __restrict__ b2,
    unsigned short* __restrict__ h2b) {
    int L = threadIdx.x & 63;
    int wid = threadIdx.x >> 6;
    int n0 = blockIdx.x * 64 + wid * 16;
    if (n0 >= N_NODES) return;
    int m = L & 15, q = L >> 4;
    int nrow = min(n0 + m, N_NODES - 1);

#define LOADB(i) s8v B##i = *(const s8v*)(wp + (i) * 512 + L * 8)
    LOADB(0); LOADB(1); LOADB(2); LOADB(3);
    LOADB(4); LOADB(5); LOADB(6); LOADB(7);
    LOADB(8); LOADB(9); LOADB(10); LOADB(11);
    LOADB(12); LOADB(13); LOADB(14); LOADB(15);
#undef LOADB

    const s8v a0 = *(const s8v*)(agg2b + (size_t)nrow * 64 + q * 8);
    const s8v a1 = *(const s8v*)(agg2b + (size_t)nrow * 64 + 32 + q * 8);
    const s8v a2 = *(const s8v*)(h1b   + (size_t)nrow * 64 + q * 8);
    const s8v a3 = *(const s8v*)(h1b   + (size_t)nrow * 64 + 32 + q * 8);

    f4v acc0 = {0.f, 0.f, 0.f, 0.f}, acc1 = acc0, acc2 = acc0, acc3 = acc0;
    acc0 = __builtin_amdgcn_mfma_f32_16x16x32_bf16(a0, B0,  acc0, 0, 0, 0);
    acc0 = __builtin_amdgcn_mfma_f32_16x16x32_bf16(a1, B4,  acc0, 0, 0, 0);
    acc0 = __builtin_amdgcn_mfma_f32_16x16x32_bf16(a2, B8,  acc0, 0, 0, 0);
    acc0 = __builtin_amdgcn_mfma_f32_16x16x32_bf16(a3, B12, acc0, 0, 0, 0);
    acc1 = __builtin_amdgcn_mfma_f32_16x16x32_bf16(a0, B1,  acc1, 0, 0, 0);
    acc1 = __builtin_amdgcn_mfma_f32_16x16x32_bf16(a1, B5,  acc1, 0, 0, 0);
    acc1 = __builtin_amdgcn_mfma_f32_16x16x32_bf16(a2, B9,  acc1, 0, 0, 0);
    acc1 = __builtin_amdgcn_mfma_f32_16x16x32_bf16(a3, B13, acc1, 0, 0, 0);
    acc2 = __builtin_amdgcn_mfma_f32_16x16x32_bf16(a0, B2,  acc2, 0, 0, 0);
    acc2 = __builtin_amdgcn_mfma_f32_16x16x32_bf16(a1, B6,  acc2, 0, 0, 0);
    acc2 = __builtin_amdgcn_mfma_f32_16x16x32_bf16(a2, B10, acc2, 0, 0, 0);
    acc2 = __builtin_amdgcn_mfma_f32_16x16x32_bf16(a3, B14, acc2, 0, 0, 0);
    acc3 = __builtin_amdgcn_mfma_f32_16x16x32_bf16(a0, B3,  acc3, 0, 0, 0);
    acc3 = __builtin_amdgcn_mfma_f32_16x16x32_bf16(a1, B7,  acc3, 0, 0, 0);
    acc3 = __builtin_amdgcn_mfma_f32_16x16x32_bf16(a2, B11, acc3, 0, 0, 0);
    acc3 = __builtin_amdgcn_mfma_f32_16x16x32_bf16(a3, B15, acc3, 0, 0, 0);

    int fcol = L & 15;
    float bia0 = b2[fcol], bia1 = b2[16 + fcol], bia2 = b2[32 + fcol], bia3 = b2[48 + fcol];
    int rbase = n0 + q * 4;
#pragma unroll
    for (int r = 0; r < 4; r++) {
        int n = rbase + r;
        if (n < N_NODES) {
            size_t o = (size_t)n * 64 + fcol;
            h2b[o]      = f2bf(fmaxf(acc0[r] + bia0, 0.0f));
            h2b[o + 16] = f2bf(fmaxf(acc1[r] + bia1, 0.0f));
            h2b[o + 32] = f2bf(fmaxf(acc2[r] + bia2, 0.0f));
            h2b[o + 48] = f2bf(fmaxf(acc3[r] + bia3, 0.0f));
        }
    }
}

// ---- mean-pool: 4 waves per graph, branch-free strided accumulate ----
__global__ __launch_bounds__(256) void k_pool2(
    const unsigned short* __restrict__ h2b, const int* __restrict__ gstart,
    float* __restrict__ pooled) {
    int w = (blockIdx.x * 256 + threadIdx.x) >> 6;
    int f = threadIdx.x & 63;
    int g = w >> 2;
    int q = w & 3;
    if (g >= N_GRAPHS) return;
    int ns = gstart[g], ne = gstart[g + 1];
    float s = 0.0f;
    int n = ns + q;
    for (; n + 12 < ne; n += 16) {
        float v0 = bf2f(h2b[(size_t)(n)      * 64 + f]);
        float v1 = bf2f(h2b[(size_t)(n + 4)  * 64 + f]);
        float v2 = bf2f(h2b[(size_t)(n + 8)  * 64 + f]);
        float v3 = bf2f(h2b[(size_t)(n + 12) * 64 + f]);
        s += (v0 + v1) + (v2 + v3);
    }
    for (; n < ne; n += 4) s += bf2f(h2b[(size_t)n * 64 + f]);
    atomicAdd(&pooled[g * 64 + f], s / fmaxf((float)(ne - ns), 1.0f));
}

// ---- classifier ----
__global__ void k_cls(const float* __restrict__ pooled, const float* __restrict__ Wc,
                      const float* __restrict__ bc, float* __restrict__ out) {
    __shared__ float rowv[64];
    int g = blockIdx.x;
    int f = threadIdx.x;
    rowv[f] = pooled[g * 64 + f];
    __syncthreads();
    if (f < NCLS) {
        float acc = bc[f];
#pragma unroll
        for (int kk = 0; kk < 64; kk++) acc += rowv[kk] * Wc[kk * NCLS + f];
        out[g * NCLS + f] = acc;
    }
}

extern "C" void kernel_launch(void* const* d_in, const int* in_sizes, int n_in,
                              void* d_out, int out_size, void* d_ws, size_t ws_size,
                              hipStream_t stream) {
    const float* x     = (const float*)d_in[0];
    const int*   eidx  = (const int*)d_in[1];
    const int*   batch = (const int*)d_in[2];
    const float* W1l   = (const float*)d_in[3];
    const float* b1    = (const float*)d_in[4];
    const float* W1r   = (const float*)d_in[5];
    const float* W2l   = (const float*)d_in[6];
    const float* b2    = (const float*)d_in[7];
    const float* W2r   = (const float*)d_in[8];
    const float* Wc    = (const float*)d_in[9];
    const float* bc    = (const float*)d_in[10];
    float* out = (float*)d_out;

    const int* src = eidx;
    const int* dst = eidx + N_EDGES;

    // workspace ≈ 39.9 MB (proven-safe envelope 40.67 MB)
    char* p = (char*)d_ws;
    unsigned int* bins    = (unsigned int*)p;   p += (size_t)N_EDGES * 4;        // 12.8 MB
    unsigned short* h1b   = (unsigned short*)p; p += (size_t)N_NODES * 64 * 2;   // 12.8 MB
    unsigned short* agg2b = (unsigned short*)p; p += (size_t)N_NODES * 64 * 2;   // 12.8 MB
    int* gh    = (int*)p;                       p += (size_t)SCAN_N * 4;         // 0.40 MB
    int* bsum  = (int*)p;                       p += 128 * 4;
    int* row   = (int*)p;                       p += (size_t)(N_NODES + 1) * 4;  // 0.40 MB
    int* gstart= (int*)p;                       p += (N_GRAPHS + 1) * 4;
    unsigned short* wp = (unsigned short*)p;    p += 8192 * 2;                   // 16 KB
    // ---- zeroed region ----
    float* pooled = (float*)p;                  p += (size_t)N_GRAPHS * 64 * 4;
    size_t zero_bytes = (size_t)(N_GRAPHS * 64) * 4;

    // h2b aliases bins: bins is dead after k_gather2
    unsigned short* h2b = (unsigned short*)bins;

    hipMemsetAsync(pooled, 0, zero_bytes, stream);

    k_prep <<<37, 256, 0, stream>>>(W2l, W2r, wp, batch, gstart);
    k_hist <<<NB, 256, 0, stream>>>(dst, gh);
    k_scan1<<<SCAN_NB1, 256, 0, stream>>>(gh, bsum);
    k_scan2<<<1, 64, 0, stream>>>(bsum);
    k_bin  <<<NB, 256, 0, stream>>>(src, dst, gh, bsum, bins);
    k_build<<<NBKT, 256, 0, stream>>>(gh, bsum, bins, row);

    k_l1f      <<<(N_NODES + 255) / 256, 256, 0, stream>>>(row, bins, x, W1l, b1, W1r, h1b);
    k_gather2  <<<2048, 256, 0, stream>>>(row, bins, h1b, agg2b);
    k_gemv_mfma<<<(N_NODES + 63) / 64, 256, 0, stream>>>(agg2b, h1b, wp, b2, h2b);
    k_pool2    <<<(N_GRAPHS * 4 * 64) / 256, 256, 0, stream>>>(h2b, gstart, pooled);
    k_cls      <<<N_GRAPHS, 64, 0, stream>>>(pooled, Wc, bc, out);
}

// Round 16
// 253.454 us; speedup vs baseline: 1.7240x; 1.0616x over previous
//
#include <hip/hip_runtime.h>

#define N_NODES 100000
#define N_EDGES 3200000
#define N_GRAPHS 1024
#define NCLS 21
#define NBKT 196          // buckets of 512 nodes
#define CAP 17408         // padded bucket capacity (mean 16384, sigma~128 -> +8 sigma)
#define NB 512            // streaming blocks for binning
#define CHUNK 6250        // N_EDGES / NB

typedef short s8v __attribute__((ext_vector_type(8)));
typedef float f4v __attribute__((ext_vector_type(4)));

__device__ __forceinline__ float bf2f(unsigned short u) {
    return __uint_as_float(((unsigned)u) << 16);
}
__device__ __forceinline__ unsigned short f2bf(float f) {
    unsigned u = __float_as_uint(f);
    unsigned r = 0x7fffu + ((u >> 16) & 1u);   // RNE
    return (unsigned short)((u + r) >> 16);
}
__device__ __forceinline__ float lo2f(unsigned w) { return __uint_as_float(w << 16); }
__device__ __forceinline__ float hi2f(unsigned w) { return __uint_as_float(w & 0xffff0000u); }

// ---- fused prep: wp pack (blocks 0-31), gstart (32-36), gcur init (37) ----
__global__ void k_prep(const float* __restrict__ W2l, const float* __restrict__ W2r,
                       unsigned short* __restrict__ wp,
                       const int* __restrict__ batch, int* __restrict__ gstart,
                       int* __restrict__ gcur) {
    if (blockIdx.x < 32) {
        int tid = blockIdx.x * 256 + threadIdx.x;   // 8192 total
        int frag = tid >> 9;
        int r = tid & 511;
        int L = r >> 3, j = r & 7;
        int kstep = frag >> 2, nt = frag & 3;
        int k = kstep * 32 + (L >> 4) * 8 + j;
        int n = nt * 16 + (L & 15);
        float val = (k < 64) ? W2l[k * 64 + n] : W2r[(k - 64) * 64 + n];
        wp[tid] = f2bf(val);
    } else if (blockIdx.x < 37) {
        int g = (blockIdx.x - 32) * 256 + threadIdx.x;
        if (g > N_GRAPHS) return;
        if (g == N_GRAPHS) { gstart[N_GRAPHS] = N_NODES; return; }
        int lo = 0, hi = N_NODES;
        while (lo < hi) { int m = (lo + hi) >> 1; if (batch[m] < g) lo = m + 1; else hi = m; }
        gstart[g] = lo;
    } else {
        int i = threadIdx.x;
        if (i < NBKT) gcur[i] = i * CAP;
    }
}

// ---- single-pass bin: LDS count -> global run reservation -> LDS scatter ----
// payload: (src << 9) | (dst & 511); bucket = dst >> 9 (kept in bbuf)
__global__ __launch_bounds__(256) void k_binone(const int* __restrict__ src,
                                                const int* __restrict__ dst,
                                                int* __restrict__ gcur,
                                                unsigned int* __restrict__ bins) {
    __shared__ unsigned int ebuf[CHUNK];        // 25 KB
    __shared__ unsigned char bbuf[CHUNK];       // 6.25 KB
    __shared__ int lh[NBKT];
    __shared__ int lbase[NBKT];
    int t = threadIdx.x;
    for (int i = t; i < NBKT; i += 256) lh[i] = 0;
    __syncthreads();
    const int2* s2 = (const int2*)(src + blockIdx.x * CHUNK);
    const int2* d2 = (const int2*)(dst + blockIdx.x * CHUNK);
    for (int i = t; i < CHUNK / 2; i += 256) {
        int2 s = s2[i];
        int2 d = d2[i];
        uint2 pp;
        pp.x = ((unsigned)s.x << 9) | (unsigned)(d.x & 511);
        pp.y = ((unsigned)s.y << 9) | (unsigned)(d.y & 511);
        *(uint2*)(&ebuf[2 * i]) = pp;
        bbuf[2 * i]     = (unsigned char)(d.x >> 9);
        bbuf[2 * i + 1] = (unsigned char)(d.y >> 9);
        atomicAdd(&lh[d.x >> 9], 1);
        atomicAdd(&lh[d.y >> 9], 1);
    }
    __syncthreads();
    for (int i = t; i < NBKT; i += 256)
        lbase[i] = atomicAdd(&gcur[i], lh[i]);   // reserve contiguous run
    __syncthreads();
    for (int i = t; i < NBKT; i += 256) lh[i] = lbase[i];   // reuse as cursor
    __syncthreads();
    for (int i = t; i < CHUNK; i += 256) {
        int b = (int)bbuf[i];
        int pos = atomicAdd(&lh[b], 1);
        if (pos < (b + 1) * CAP) bins[pos] = ebuf[i];   // overflow-guarded
    }
}

// ---- per-bucket: slurp -> hist -> scan -> row/deg + in-place CSR + fused layer-1 ----
__global__ __launch_bounds__(256) void k_build(
    const int* __restrict__ gcur, unsigned int* __restrict__ bins,
    int* __restrict__ row, unsigned short* __restrict__ deg,
    const float* __restrict__ x,
    const float* __restrict__ W1l, const float* __restrict__ b1,
    const float* __restrict__ W1r, unsigned short* __restrict__ h1b) {
    __shared__ unsigned int ebuf[CAP];   // 68 KB
    __shared__ int hist[512];
    __shared__ int curs[512];
    __shared__ int lds[256];
    __shared__ float t1[512];
    int k = blockIdx.x, t = threadIdx.x;
    int e0 = k * CAP;
    int cnt = min(gcur[k] - e0, CAP);
    hist[t] = 0; hist[t + 256] = 0;
    t1[t] = 0.0f; t1[t + 256] = 0.0f;
    __syncthreads();
    for (int i = t; i < cnt; i += 256) {
        unsigned p = bins[e0 + i];
        ebuf[i] = p;
        atomicAdd(&hist[p & 511u], 1);
    }
    __syncthreads();
    int h0 = hist[2 * t], h1 = hist[2 * t + 1];
    lds[t] = h0 + h1;
    __syncthreads();
    for (int off = 1; off < 256; off <<= 1) {
        int cur = lds[t];
        int add = (t >= off) ? lds[t - off] : 0;
        __syncthreads();
        lds[t] = cur + add;
        __syncthreads();
    }
    int run = e0 + lds[t] - (h0 + h1);
    curs[2 * t] = run;
    curs[2 * t + 1] = run + h0;
    int n0w = k * 512 + 2 * t;
    if (n0w < N_NODES) { row[n0w] = run; deg[n0w] = (unsigned short)h0; }
    if (n0w + 1 < N_NODES) { row[n0w + 1] = run + h0; deg[n0w + 1] = (unsigned short)h1; }
    __syncthreads();
    // scatter to exact CSR + layer-1 scalar aggregation (x is L2-resident)
    for (int i = t; i < cnt; i += 256) {
        unsigned p = ebuf[i];
        int slot = (int)(p & 511u);
        int pos = atomicAdd(&curs[slot], 1);
        bins[pos] = p >> 9;
        atomicAdd(&t1[slot], x[p >> 9]);
    }
    __syncthreads();
    // layer-1 node update for this bucket's 512 nodes
    for (int i = t; i < 512 * 64; i += 256) {
        int slot = i >> 6, f = i & 63;
        int n = k * 512 + slot;
        if (n >= N_NODES) break;
        float a = t1[slot] / fmaxf((float)hist[slot], 1.0f);
        float v = a * W1l[f] + b1[f] + x[n] * W1r[f];
        h1b[(size_t)n * 64 + f] = f2bf(fmaxf(v, 0.0f));
    }
}

// ---- layer 2 gather: 8 edges x 8 features; r1 from deg[] (padded-CSR-safe) ----
__global__ __launch_bounds__(256) void k_gather2(
    const int* __restrict__ row, const unsigned short* __restrict__ deg,
    const unsigned int* __restrict__ csr,
    const unsigned short* __restrict__ h1b,
    unsigned short* __restrict__ agg2b) {
    int gw = (blockIdx.x * 256 + threadIdx.x) >> 6;
    int L = threadIdx.x & 63;
    int fo = L & 7;
    int es = L >> 3;
    int nw = gridDim.x * 4;
    for (int n = gw; n < N_NODES; n += nw) {
        int r0 = row[n];
        int dn = (int)deg[n];
        int r1 = r0 + dn;
        float a0 = 0.f, a1 = 0.f, a2 = 0.f, a3 = 0.f,
              a4 = 0.f, a5 = 0.f, a6 = 0.f, a7 = 0.f;
        int base = r0;
        for (; base + 32 <= r1; base += 32) {
            int sA = (int)csr[base + es];
            int sB = (int)csr[base + 8 + es];
            int sC = (int)csr[base + 16 + es];
            int sD = (int)csr[base + 24 + es];
            uint4 dA = *(const uint4*)(h1b + (size_t)sA * 64 + fo * 8);
            uint4 dB = *(const uint4*)(h1b + (size_t)sB * 64 + fo * 8);
            uint4 dC = *(const uint4*)(h1b + (size_t)sC * 64 + fo * 8);
            uint4 dD = *(const uint4*)(h1b + (size_t)sD * 64 + fo * 8);
            a0 += lo2f(dA.x); a1 += hi2f(dA.x); a2 += lo2f(dA.y); a3 += hi2f(dA.y);
            a4 += lo2f(dA.z); a5 += hi2f(dA.z); a6 += lo2f(dA.w); a7 += hi2f(dA.w);
            a0 += lo2f(dB.x); a1 += hi2f(dB.x); a2 += lo2f(dB.y); a3 += hi2f(dB.y);
            a4 += lo2f(dB.z); a5 += hi2f(dB.z); a6 += lo2f(dB.w); a7 += hi2f(dB.w);
            a0 += lo2f(dC.x); a1 += hi2f(dC.x); a2 += lo2f(dC.y); a3 += hi2f(dC.y);
            a4 += lo2f(dC.z); a5 += hi2f(dC.z); a6 += lo2f(dC.w); a7 += hi2f(dC.w);
            a0 += lo2f(dD.x); a1 += hi2f(dD.x); a2 += lo2f(dD.y); a3 += hi2f(dD.y);
            a4 += lo2f(dD.z); a5 += hi2f(dD.z); a6 += lo2f(dD.w); a7 += hi2f(dD.w);
        }
        for (; base + 16 <= r1; base += 16) {
            int sA = (int)csr[base + es];
            int sB = (int)csr[base + 8 + es];
            uint4 dA = *(const uint4*)(h1b + (size_t)sA * 64 + fo * 8);
            uint4 dB = *(const uint4*)(h1b + (size_t)sB * 64 + fo * 8);
            a0 += lo2f(dA.x); a1 += hi2f(dA.x); a2 += lo2f(dA.y); a3 += hi2f(dA.y);
            a4 += lo2f(dA.z); a5 += hi2f(dA.z); a6 += lo2f(dA.w); a7 += hi2f(dA.w);
            a0 += lo2f(dB.x); a1 += hi2f(dB.x); a2 += lo2f(dB.y); a3 += hi2f(dB.y);
            a4 += lo2f(dB.z); a5 += hi2f(dB.z); a6 += lo2f(dB.w); a7 += hi2f(dB.w);
        }
        for (; base < r1; base += 8) {
            int e = base + es;
            bool act = e < r1;
            int sA = (int)csr[act ? e : r1 - 1];
            uint4 d = *(const uint4*)(h1b + (size_t)sA * 64 + fo * 8);
            unsigned m = act ? 0xffffffffu : 0u;
            d.x &= m; d.y &= m; d.z &= m; d.w &= m;
            a0 += lo2f(d.x); a1 += hi2f(d.x); a2 += lo2f(d.y); a3 += hi2f(d.y);
            a4 += lo2f(d.z); a5 += hi2f(d.z); a6 += lo2f(d.w); a7 += hi2f(d.w);
        }
        {
            bool hi = (es & 4) != 0;
            float s0 = hi ? a0 : a4, s1 = hi ? a1 : a5, s2 = hi ? a2 : a6, s3 = hi ? a3 : a7;
            float r0v = __shfl_xor(s0, 32, 64);
            float r1v = __shfl_xor(s1, 32, 64);
            float r2v = __shfl_xor(s2, 32, 64);
            float r3v = __shfl_xor(s3, 32, 64);
            a0 = (hi ? a4 : a0) + r0v;
            a1 = (hi ? a5 : a1) + r1v;
            a2 = (hi ? a6 : a2) + r2v;
            a3 = (hi ? a7 : a3) + r3v;
        }
        {
            bool hi = (es & 2) != 0;
            float s0 = hi ? a0 : a2, s1 = hi ? a1 : a3;
            float r0v = __shfl_xor(s0, 16, 64);
            float r1v = __shfl_xor(s1, 16, 64);
            a0 = (hi ? a2 : a0) + r0v;
            a1 = (hi ? a3 : a1) + r1v;
        }
        {
            bool hi = (es & 1) != 0;
            float s0 = hi ? a0 : a1;
            float r0v = __shfl_xor(s0, 8, 64);
            a0 = (hi ? a1 : a0) + r0v;
        }
        float inv = 1.0f / fmaxf((float)dn, 1.0f);
        agg2b[(size_t)n * 64 + fo * 8 + es] = f2bf(a0 * inv);
    }
}

// ---- layer 2 GEMM via MFMA: [16 nodes x 128] x [128 x 64] per wave ----
__global__ __launch_bounds__(256) void k_gemv_mfma(
    const unsigned short* __restrict__ agg2b, const unsigned short* __restrict__ h1b,
    const unsigned short* __restrict__ wp, const float* __restrict__ b2,
    unsigned short* __restrict__ h2b) {
    int L = threadIdx.x & 63;
    int wid = threadIdx.x >> 6;
    int n0 = blockIdx.x * 64 + wid * 16;
    if (n0 >= N_NODES) return;
    int m = L & 15, q = L >> 4;
    int nrow = min(n0 + m, N_NODES - 1);

#define LOADB(i) s8v B##i = *(const s8v*)(wp + (i) * 512 + L * 8)
    LOADB(0); LOADB(1); LOADB(2); LOADB(3);
    LOADB(4); LOADB(5); LOADB(6); LOADB(7);
    LOADB(8); LOADB(9); LOADB(10); LOADB(11);
    LOADB(12); LOADB(13); LOADB(14); LOADB(15);
#undef LOADB

    const s8v a0 = *(const s8v*)(agg2b + (size_t)nrow * 64 + q * 8);
    const s8v a1 = *(const s8v*)(agg2b + (size_t)nrow * 64 + 32 + q * 8);
    const s8v a2 = *(const s8v*)(h1b   + (size_t)nrow * 64 + q * 8);
    const s8v a3 = *(const s8v*)(h1b   + (size_t)nrow * 64 + 32 + q * 8);

    f4v acc0 = {0.f, 0.f, 0.f, 0.f}, acc1 = acc0, acc2 = acc0, acc3 = acc0;
    acc0 = __builtin_amdgcn_mfma_f32_16x16x32_bf16(a0, B0,  acc0, 0, 0, 0);
    acc0 = __builtin_amdgcn_mfma_f32_16x16x32_bf16(a1, B4,  acc0, 0, 0, 0);
    acc0 = __builtin_amdgcn_mfma_f32_16x16x32_bf16(a2, B8,  acc0, 0, 0, 0);
    acc0 = __builtin_amdgcn_mfma_f32_16x16x32_bf16(a3, B12, acc0, 0, 0, 0);
    acc1 = __builtin_amdgcn_mfma_f32_16x16x32_bf16(a0, B1,  acc1, 0, 0, 0);
    acc1 = __builtin_amdgcn_mfma_f32_16x16x32_bf16(a1, B5,  acc1, 0, 0, 0);
    acc1 = __builtin_amdgcn_mfma_f32_16x16x32_bf16(a2, B9,  acc1, 0, 0, 0);
    acc1 = __builtin_amdgcn_mfma_f32_16x16x32_bf16(a3, B13, acc1, 0, 0, 0);
    acc2 = __builtin_amdgcn_mfma_f32_16x16x32_bf16(a0, B2,  acc2, 0, 0, 0);
    acc2 = __builtin_amdgcn_mfma_f32_16x16x32_bf16(a1, B6,  acc2, 0, 0, 0);
    acc2 = __builtin_amdgcn_mfma_f32_16x16x32_bf16(a2, B10, acc2, 0, 0, 0);
    acc2 = __builtin_amdgcn_mfma_f32_16x16x32_bf16(a3, B14, acc2, 0, 0, 0);
    acc3 = __builtin_amdgcn_mfma_f32_16x16x32_bf16(a0, B3,  acc3, 0, 0, 0);
    acc3 = __builtin_amdgcn_mfma_f32_16x16x32_bf16(a1, B7,  acc3, 0, 0, 0);
    acc3 = __builtin_amdgcn_mfma_f32_16x16x32_bf16(a2, B11, acc3, 0, 0, 0);
    acc3 = __builtin_amdgcn_mfma_f32_16x16x32_bf16(a3, B15, acc3, 0, 0, 0);

    int fcol = L & 15;
    float bia0 = b2[fcol], bia1 = b2[16 + fcol], bia2 = b2[32 + fcol], bia3 = b2[48 + fcol];
    int rbase = n0 + q * 4;
#pragma unroll
    for (int r = 0; r < 4; r++) {
        int n = rbase + r;
        if (n < N_NODES) {
            size_t o = (size_t)n * 64 + fcol;
            h2b[o]      = f2bf(fmaxf(acc0[r] + bia0, 0.0f));
            h2b[o + 16] = f2bf(fmaxf(acc1[r] + bia1, 0.0f));
            h2b[o + 32] = f2bf(fmaxf(acc2[r] + bia2, 0.0f));
            h2b[o + 48] = f2bf(fmaxf(acc3[r] + bia3, 0.0f));
        }
    }
}

// ---- mean-pool: 1 wave per graph, plain store (no memset, no atomics) ----
__global__ __launch_bounds__(256) void k_pool3(
    const unsigned short* __restrict__ h2b, const int* __restrict__ gstart,
    float* __restrict__ pooled) {
    int g = (blockIdx.x * 256 + threadIdx.x) >> 6;
    int f = threadIdx.x & 63;
    if (g >= N_GRAPHS) return;
    int ns = gstart[g], ne = gstart[g + 1];
    float s = 0.0f;
    int n = ns;
    for (; n + 3 < ne; n += 4) {
        float v0 = bf2f(h2b[(size_t)(n)     * 64 + f]);
        float v1 = bf2f(h2b[(size_t)(n + 1) * 64 + f]);
        float v2 = bf2f(h2b[(size_t)(n + 2) * 64 + f]);
        float v3 = bf2f(h2b[(size_t)(n + 3) * 64 + f]);
        s += (v0 + v1) + (v2 + v3);
    }
    for (; n < ne; n++) s += bf2f(h2b[(size_t)n * 64 + f]);
    pooled[g * 64 + f] = s / fmaxf((float)(ne - ns), 1.0f);
}

// ---- classifier ----
__global__ void k_cls(const float* __restrict__ pooled, const float* __restrict__ Wc,
                      const float* __restrict__ bc, float* __restrict__ out) {
    __shared__ float rowv[64];
    int g = blockIdx.x;
    int f = threadIdx.x;
    rowv[f] = pooled[g * 64 + f];
    __syncthreads();
    if (f < NCLS) {
        float acc = bc[f];
#pragma unroll
        for (int kk = 0; kk < 64; kk++) acc += rowv[kk] * Wc[kk * NCLS + f];
        out[g * NCLS + f] = acc;
    }
}

extern "C" void kernel_launch(void* const* d_in, const int* in_sizes, int n_in,
                              void* d_out, int out_size, void* d_ws, size_t ws_size,
                              hipStream_t stream) {
    const float* x     = (const float*)d_in[0];
    const int*   eidx  = (const int*)d_in[1];
    const int*   batch = (const int*)d_in[2];
    const float* W1l   = (const float*)d_in[3];
    const float* b1    = (const float*)d_in[4];
    const float* W1r   = (const float*)d_in[5];
    const float* W2l   = (const float*)d_in[6];
    const float* b2    = (const float*)d_in[7];
    const float* W2r   = (const float*)d_in[8];
    const float* Wc    = (const float*)d_in[9];
    const float* bc    = (const float*)d_in[10];
    float* out = (float*)d_out;

    const int* src = eidx;
    const int* dst = eidx + N_EDGES;

    // workspace ≈ 40.15 MB (R1 passed with 40.67 MB)
    char* p = (char*)d_ws;
    unsigned int* bins    = (unsigned int*)p;   p += (size_t)NBKT * CAP * 4;     // 13.65 MB
    unsigned short* h1b   = (unsigned short*)p; p += (size_t)N_NODES * 64 * 2;   // 12.8 MB
    unsigned short* agg2b = (unsigned short*)p; p += (size_t)N_NODES * 64 * 2;   // 12.8 MB
    int* row   = (int*)p;                       p += (size_t)(N_NODES + 1) * 4;  // 0.40 MB
    unsigned short* deg = (unsigned short*)p;   p += (size_t)N_NODES * 2;        // 0.20 MB
    int* gcur  = (int*)p;                       p += NBKT * 4;
    int* gstart= (int*)p;                       p += (N_GRAPHS + 1) * 4;
    unsigned short* wp = (unsigned short*)p;    p += 8192 * 2;                   // 16 KB
    float* pooled = (float*)p;                  p += (size_t)N_GRAPHS * 64 * 4;  // 0.26 MB

    // h2b aliases bins: bins (CSR) is dead after k_gather2
    unsigned short* h2b = (unsigned short*)bins;

    k_prep  <<<38, 256, 0, stream>>>(W2l, W2r, wp, batch, gstart, gcur);
    k_binone<<<NB, 256, 0, stream>>>(src, dst, gcur, bins);
    k_build <<<NBKT, 256, 0, stream>>>(gcur, bins, row, deg, x, W1l, b1, W1r, h1b);

    k_gather2  <<<2048, 256, 0, stream>>>(row, deg, bins, h1b, agg2b);
    k_gemv_mfma<<<(N_NODES + 63) / 64, 256, 0, stream>>>(agg2b, h1b, wp, b2, h2b);
    k_pool3    <<<(N_GRAPHS * 64) / 256, 256, 0, stream>>>(h2b, gstart, pooled);
    k_cls      <<<N_GRAPHS, 64, 0, stream>>>(pooled, Wc, bc, out);
}

// Round 17
// 244.425 us; speedup vs baseline: 1.7876x; 1.0369x over previous
//
#include <hip/hip_runtime.h>

#define N_NODES 100000
#define N_EDGES 3200000
#define N_GRAPHS 1024
#define NCLS 21
#define NBKT 782          // buckets of 128 nodes: ceil(100000/128)
#define CAP 4480          // padded bucket capacity (mean 4096, sigma 64 -> +6 sigma)
#define NB 512            // streaming blocks for binning
#define CHUNK 6250        // N_EDGES / NB

typedef short s8v __attribute__((ext_vector_type(8)));
typedef float f4v __attribute__((ext_vector_type(4)));

__device__ __forceinline__ float bf2f(unsigned short u) {
    return __uint_as_float(((unsigned)u) << 16);
}
__device__ __forceinline__ unsigned short f2bf(float f) {
    unsigned u = __float_as_uint(f);
    unsigned r = 0x7fffu + ((u >> 16) & 1u);   // RNE
    return (unsigned short)((u + r) >> 16);
}
__device__ __forceinline__ float lo2f(unsigned w) { return __uint_as_float(w << 16); }
__device__ __forceinline__ float hi2f(unsigned w) { return __uint_as_float(w & 0xffff0000u); }

// ---- fused prep: wp pack (blocks 0-31), gstart (32-36), gcur init (37) ----
__global__ void k_prep(const float* __restrict__ W2l, const float* __restrict__ W2r,
                       unsigned short* __restrict__ wp,
                       const int* __restrict__ batch, int* __restrict__ gstart,
                       int* __restrict__ gcur) {
    if (blockIdx.x < 32) {
        int tid = blockIdx.x * 256 + threadIdx.x;   // 8192 total
        int frag = tid >> 9;
        int r = tid & 511;
        int L = r >> 3, j = r & 7;
        int kstep = frag >> 2, nt = frag & 3;
        int k = kstep * 32 + (L >> 4) * 8 + j;
        int n = nt * 16 + (L & 15);
        float val = (k < 64) ? W2l[k * 64 + n] : W2r[(k - 64) * 64 + n];
        wp[tid] = f2bf(val);
    } else if (blockIdx.x < 37) {
        int g = (blockIdx.x - 32) * 256 + threadIdx.x;
        if (g > N_GRAPHS) return;
        if (g == N_GRAPHS) { gstart[N_GRAPHS] = N_NODES; return; }
        int lo = 0, hi = N_NODES;
        while (lo < hi) { int m = (lo + hi) >> 1; if (batch[m] < g) lo = m + 1; else hi = m; }
        gstart[g] = lo;
    } else {
        for (int i = threadIdx.x; i < NBKT; i += 256) gcur[i] = i * CAP;
    }
}

// ---- single-pass bin: LDS count -> global run reservation -> LDS scatter ----
// payload: (src << 7) | (dst & 127); bucket = dst >> 7 (kept in bbuf, ushort)
__global__ __launch_bounds__(256) void k_binone(const int* __restrict__ src,
                                                const int* __restrict__ dst,
                                                int* __restrict__ gcur,
                                                unsigned int* __restrict__ bins) {
    __shared__ unsigned int ebuf[CHUNK];         // 25 KB
    __shared__ unsigned short bbuf[CHUNK];       // 12.5 KB
    __shared__ int lh[NBKT];                     // 3.1 KB
    __shared__ int lbase[NBKT];                  // 3.1 KB
    int t = threadIdx.x;
    for (int i = t; i < NBKT; i += 256) lh[i] = 0;
    __syncthreads();
    const int2* s2 = (const int2*)(src + blockIdx.x * CHUNK);
    const int2* d2 = (const int2*)(dst + blockIdx.x * CHUNK);
    for (int i = t; i < CHUNK / 2; i += 256) {
        int2 s = s2[i];
        int2 d = d2[i];
        uint2 pp;
        pp.x = ((unsigned)s.x << 7) | (unsigned)(d.x & 127);
        pp.y = ((unsigned)s.y << 7) | (unsigned)(d.y & 127);
        *(uint2*)(&ebuf[2 * i]) = pp;
        bbuf[2 * i]     = (unsigned short)(d.x >> 7);
        bbuf[2 * i + 1] = (unsigned short)(d.y >> 7);
        atomicAdd(&lh[d.x >> 7], 1);
        atomicAdd(&lh[d.y >> 7], 1);
    }
    __syncthreads();
    for (int i = t; i < NBKT; i += 256)
        lbase[i] = atomicAdd(&gcur[i], lh[i]);   // reserve contiguous run
    __syncthreads();
    for (int i = t; i < NBKT; i += 256) lh[i] = lbase[i];   // reuse as cursor
    __syncthreads();
    for (int i = t; i < CHUNK; i += 256) {
        int b = (int)bbuf[i];
        int pos = atomicAdd(&lh[b], 1);
        if (pos < (b + 1) * CAP) bins[pos] = ebuf[i];   // overflow-guarded
    }
}

// ---- per-bucket (128 nodes): slurp -> hist -> scan -> row/deg + CSR + layer-1 ----
__global__ __launch_bounds__(256) void k_build(
    const int* __restrict__ gcur, unsigned int* __restrict__ bins,
    int* __restrict__ row, unsigned short* __restrict__ deg,
    const float* __restrict__ x,
    const float* __restrict__ W1l, const float* __restrict__ b1,
    const float* __restrict__ W1r, unsigned short* __restrict__ h1b) {
    __shared__ unsigned int ebuf[CAP];   // 17.9 KB
    __shared__ int hist[128];
    __shared__ int curs[128];
    __shared__ int lds[128];
    __shared__ float t1[128];
    int k = blockIdx.x, t = threadIdx.x;
    int e0 = k * CAP;
    int cnt = min(gcur[k] - e0, CAP);
    if (t < 128) { hist[t] = 0; t1[t] = 0.0f; }
    __syncthreads();
    for (int i = t; i < cnt; i += 256) {
        unsigned p = bins[e0 + i];
        ebuf[i] = p;
        atomicAdd(&hist[p & 127u], 1);
    }
    __syncthreads();
    if (t < 128) lds[t] = hist[t];
    __syncthreads();
    for (int off = 1; off < 128; off <<= 1) {
        int cur = (t < 128) ? lds[t] : 0;
        int add = (t < 128 && t >= off) ? lds[t - off] : 0;
        __syncthreads();
        if (t < 128) lds[t] = cur + add;
        __syncthreads();
    }
    if (t < 128) {
        int run = e0 + lds[t] - hist[t];   // exclusive start
        curs[t] = run;
        int n = k * 128 + t;
        if (n < N_NODES) { row[n] = run; deg[n] = (unsigned short)hist[t]; }
    }
    __syncthreads();
    // scatter to exact CSR + layer-1 scalar aggregation (x is L2-resident)
    for (int i = t; i < cnt; i += 256) {
        unsigned p = ebuf[i];
        int slot = (int)(p & 127u);
        int pos = atomicAdd(&curs[slot], 1);
        bins[pos] = p >> 7;
        atomicAdd(&t1[slot], x[p >> 7]);
    }
    __syncthreads();
    // layer-1 node update for this bucket's 128 nodes
    for (int i = t; i < 128 * 64; i += 256) {
        int slot = i >> 6, f = i & 63;
        int n = k * 128 + slot;
        if (n >= N_NODES) break;
        float a = t1[slot] / fmaxf((float)hist[slot], 1.0f);
        float v = a * W1l[f] + b1[f] + x[n] * W1r[f];
        h1b[(size_t)n * 64 + f] = f2bf(fmaxf(v, 0.0f));
    }
}

// ---- layer 2 gather: 8 edges x 8 features; r1 from deg[] (padded-CSR-safe) ----
__global__ __launch_bounds__(256) void k_gather2(
    const int* __restrict__ row, const unsigned short* __restrict__ deg,
    const unsigned int* __restrict__ csr,
    const unsigned short* __restrict__ h1b,
    unsigned short* __restrict__ agg2b) {
    int gw = (blockIdx.x * 256 + threadIdx.x) >> 6;
    int L = threadIdx.x & 63;
    int fo = L & 7;
    int es = L >> 3;
    int nw = gridDim.x * 4;
    for (int n = gw; n < N_NODES; n += nw) {
        int r0 = row[n];
        int dn = (int)deg[n];
        int r1 = r0 + dn;
        float a0 = 0.f, a1 = 0.f, a2 = 0.f, a3 = 0.f,
              a4 = 0.f, a5 = 0.f, a6 = 0.f, a7 = 0.f;
        int base = r0;
        for (; base + 32 <= r1; base += 32) {
            int sA = (int)csr[base + es];
            int sB = (int)csr[base + 8 + es];
            int sC = (int)csr[base + 16 + es];
            int sD = (int)csr[base + 24 + es];
            uint4 dA = *(const uint4*)(h1b + (size_t)sA * 64 + fo * 8);
            uint4 dB = *(const uint4*)(h1b + (size_t)sB * 64 + fo * 8);
            uint4 dC = *(const uint4*)(h1b + (size_t)sC * 64 + fo * 8);
            uint4 dD = *(const uint4*)(h1b + (size_t)sD * 64 + fo * 8);
            a0 += lo2f(dA.x); a1 += hi2f(dA.x); a2 += lo2f(dA.y); a3 += hi2f(dA.y);
            a4 += lo2f(dA.z); a5 += hi2f(dA.z); a6 += lo2f(dA.w); a7 += hi2f(dA.w);
            a0 += lo2f(dB.x); a1 += hi2f(dB.x); a2 += lo2f(dB.y); a3 += hi2f(dB.y);
            a4 += lo2f(dB.z); a5 += hi2f(dB.z); a6 += lo2f(dB.w); a7 += hi2f(dB.w);
            a0 += lo2f(dC.x); a1 += hi2f(dC.x); a2 += lo2f(dC.y); a3 += hi2f(dC.y);
            a4 += lo2f(dC.z); a5 += hi2f(dC.z); a6 += lo2f(dC.w); a7 += hi2f(dC.w);
            a0 += lo2f(dD.x); a1 += hi2f(dD.x); a2 += lo2f(dD.y); a3 += hi2f(dD.y);
            a4 += lo2f(dD.z); a5 += hi2f(dD.z); a6 += lo2f(dD.w); a7 += hi2f(dD.w);
        }
        for (; base + 16 <= r1; base += 16) {
            int sA = (int)csr[base + es];
            int sB = (int)csr[base + 8 + es];
            uint4 dA = *(const uint4*)(h1b + (size_t)sA * 64 + fo * 8);
            uint4 dB = *(const uint4*)(h1b + (size_t)sB * 64 + fo * 8);
            a0 += lo2f(dA.x); a1 += hi2f(dA.x); a2 += lo2f(dA.y); a3 += hi2f(dA.y);
            a4 += lo2f(dA.z); a5 += hi2f(dA.z); a6 += lo2f(dA.w); a7 += hi2f(dA.w);
            a0 += lo2f(dB.x); a1 += hi2f(dB.x); a2 += lo2f(dB.y); a3 += hi2f(dB.y);
            a4 += lo2f(dB.z); a5 += hi2f(dB.z); a6 += lo2f(dB.w); a7 += hi2f(dB.w);
        }
        for (; base < r1; base += 8) {
            int e = base + es;
            bool act = e < r1;
            int sA = (int)csr[act ? e : r1 - 1];
            uint4 d = *(const uint4*)(h1b + (size_t)sA * 64 + fo * 8);
            unsigned m = act ? 0xffffffffu : 0u;
            d.x &= m; d.y &= m; d.z &= m; d.w &= m;
            a0 += lo2f(d.x); a1 += hi2f(d.x); a2 += lo2f(d.y); a3 += hi2f(d.y);
            a4 += lo2f(d.z); a5 += hi2f(d.z); a6 += lo2f(d.w); a7 += hi2f(d.w);
        }
        {
            bool hi = (es & 4) != 0;
            float s0 = hi ? a0 : a4, s1 = hi ? a1 : a5, s2 = hi ? a2 : a6, s3 = hi ? a3 : a7;
            float r0v = __shfl_xor(s0, 32, 64);
            float r1v = __shfl_xor(s1, 32, 64);
            float r2v = __shfl_xor(s2, 32, 64);
            float r3v = __shfl_xor(s3, 32, 64);
            a0 = (hi ? a4 : a0) + r0v;
            a1 = (hi ? a5 : a1) + r1v;
            a2 = (hi ? a6 : a2) + r2v;
            a3 = (hi ? a7 : a3) + r3v;
        }
        {
            bool hi = (es & 2) != 0;
            float s0 = hi ? a0 : a2, s1 = hi ? a1 : a3;
            float r0v = __shfl_xor(s0, 16, 64);
            float r1v = __shfl_xor(s1, 16, 64);
            a0 = (hi ? a2 : a0) + r0v;
            a1 = (hi ? a3 : a1) + r1v;
        }
        {
            bool hi = (es & 1) != 0;
            float s0 = hi ? a0 : a1;
            float r0v = __shfl_xor(s0, 8, 64);
            a0 = (hi ? a1 : a0) + r0v;
        }
        float inv = 1.0f / fmaxf((float)dn, 1.0f);
        agg2b[(size_t)n * 64 + fo * 8 + es] = f2bf(a0 * inv);
    }
}

// ---- layer 2 GEMM via MFMA: [16 nodes x 128] x [128 x 64] per wave ----
__global__ __launch_bounds__(256) void k_gemv_mfma(
    const unsigned short* __restrict__ agg2b, const unsigned short* __restrict__ h1b,
    const unsigned short* __restrict__ wp, const float* __restrict__ b2,
    unsigned short* __restrict__ h2b) {
    int L = threadIdx.x & 63;
    int wid = threadIdx.x >> 6;
    int n0 = blockIdx.x * 64 + wid * 16;
    if (n0 >= N_NODES) return;
    int m = L & 15, q = L >> 4;
    int nrow = min(n0 + m, N_NODES - 1);

#define LOADB(i) s8v B##i = *(const s8v*)(wp + (i) * 512 + L * 8)
    LOADB(0); LOADB(1); LOADB(2); LOADB(3);
    LOADB(4); LOADB(5); LOADB(6); LOADB(7);
    LOADB(8); LOADB(9); LOADB(10); LOADB(11);
    LOADB(12); LOADB(13); LOADB(14); LOADB(15);
#undef LOADB

    const s8v a0 = *(const s8v*)(agg2b + (size_t)nrow * 64 + q * 8);
    const s8v a1 = *(const s8v*)(agg2b + (size_t)nrow * 64 + 32 + q * 8);
    const s8v a2 = *(const s8v*)(h1b   + (size_t)nrow * 64 + q * 8);
    const s8v a3 = *(const s8v*)(h1b   + (size_t)nrow * 64 + 32 + q * 8);

    f4v acc0 = {0.f, 0.f, 0.f, 0.f}, acc1 = acc0, acc2 = acc0, acc3 = acc0;
    acc0 = __builtin_amdgcn_mfma_f32_16x16x32_bf16(a0, B0,  acc0, 0, 0, 0);
    acc0 = __builtin_amdgcn_mfma_f32_16x16x32_bf16(a1, B4,  acc0, 0, 0, 0);
    acc0 = __builtin_amdgcn_mfma_f32_16x16x32_bf16(a2, B8,  acc0, 0, 0, 0);
    acc0 = __builtin_amdgcn_mfma_f32_16x16x32_bf16(a3, B12, acc0, 0, 0, 0);
    acc1 = __builtin_amdgcn_mfma_f32_16x16x32_bf16(a0, B1,  acc1, 0, 0, 0);
    acc1 = __builtin_amdgcn_mfma_f32_16x16x32_bf16(a1, B5,  acc1, 0, 0, 0);
    acc1 = __builtin_amdgcn_mfma_f32_16x16x32_bf16(a2, B9,  acc1, 0, 0, 0);
    acc1 = __builtin_amdgcn_mfma_f32_16x16x32_bf16(a3, B13, acc1, 0, 0, 0);
    acc2 = __builtin_amdgcn_mfma_f32_16x16x32_bf16(a0, B2,  acc2, 0, 0, 0);
    acc2 = __builtin_amdgcn_mfma_f32_16x16x32_bf16(a1, B6,  acc2, 0, 0, 0);
    acc2 = __builtin_amdgcn_mfma_f32_16x16x32_bf16(a2, B10, acc2, 0, 0, 0);
    acc2 = __builtin_amdgcn_mfma_f32_16x16x32_bf16(a3, B14, acc2, 0, 0, 0);
    acc3 = __builtin_amdgcn_mfma_f32_16x16x32_bf16(a0, B3,  acc3, 0, 0, 0);
    acc3 = __builtin_amdgcn_mfma_f32_16x16x32_bf16(a1, B7,  acc3, 0, 0, 0);
    acc3 = __builtin_amdgcn_mfma_f32_16x16x32_bf16(a2, B11, acc3, 0, 0, 0);
    acc3 = __builtin_amdgcn_mfma_f32_16x16x32_bf16(a3, B15, acc3, 0, 0, 0);

    int fcol = L & 15;
    float bia0 = b2[fcol], bia1 = b2[16 + fcol], bia2 = b2[32 + fcol], bia3 = b2[48 + fcol];
    int rbase = n0 + q * 4;
#pragma unroll
    for (int r = 0; r < 4; r++) {
        int n = rbase + r;
        if (n < N_NODES) {
            size_t o = (size_t)n * 64 + fcol;
            h2b[o]      = f2bf(fmaxf(acc0[r] + bia0, 0.0f));
            h2b[o + 16] = f2bf(fmaxf(acc1[r] + bia1, 0.0f));
            h2b[o + 32] = f2bf(fmaxf(acc2[r] + bia2, 0.0f));
            h2b[o + 48] = f2bf(fmaxf(acc3[r] + bia3, 0.0f));
        }
    }
}

// ---- mean-pool: 1 wave per graph, plain store (no memset, no atomics) ----
__global__ __launch_bounds__(256) void k_pool3(
    const unsigned short* __restrict__ h2b, const int* __restrict__ gstart,
    float* __restrict__ pooled) {
    int g = (blockIdx.x * 256 + threadIdx.x) >> 6;
    int f = threadIdx.x & 63;
    if (g >= N_GRAPHS) return;
    int ns = gstart[g], ne = gstart[g + 1];
    float s = 0.0f;
    int n = ns;
    for (; n + 3 < ne; n += 4) {
        float v0 = bf2f(h2b[(size_t)(n)     * 64 + f]);
        float v1 = bf2f(h2b[(size_t)(n + 1) * 64 + f]);
        float v2 = bf2f(h2b[(size_t)(n + 2) * 64 + f]);
        float v3 = bf2f(h2b[(size_t)(n + 3) * 64 + f]);
        s += (v0 + v1) + (v2 + v3);
    }
    for (; n < ne; n++) s += bf2f(h2b[(size_t)n * 64 + f]);
    pooled[g * 64 + f] = s / fmaxf((float)(ne - ns), 1.0f);
}

// ---- classifier ----
__global__ void k_cls(const float* __restrict__ pooled, const float* __restrict__ Wc,
                      const float* __restrict__ bc, float* __restrict__ out) {
    __shared__ float rowv[64];
    int g = blockIdx.x;
    int f = threadIdx.x;
    rowv[f] = pooled[g * 64 + f];
    __syncthreads();
    if (f < NCLS) {
        float acc = bc[f];
#pragma unroll
        for (int kk = 0; kk < 64; kk++) acc += rowv[kk] * Wc[kk * NCLS + f];
        out[g * NCLS + f] = acc;
    }
}

extern "C" void kernel_launch(void* const* d_in, const int* in_sizes, int n_in,
                              void* d_out, int out_size, void* d_ws, size_t ws_size,
                              hipStream_t stream) {
    const float* x     = (const float*)d_in[0];
    const int*   eidx  = (const int*)d_in[1];
    const int*   batch = (const int*)d_in[2];
    const float* W1l   = (const float*)d_in[3];
    const float* b1    = (const float*)d_in[4];
    const float* W1r   = (const float*)d_in[5];
    const float* W2l   = (const float*)d_in[6];
    const float* b2    = (const float*)d_in[7];
    const float* W2r   = (const float*)d_in[8];
    const float* Wc    = (const float*)d_in[9];
    const float* bc    = (const float*)d_in[10];
    float* out = (float*)d_out;

    const int* src = eidx;
    const int* dst = eidx + N_EDGES;

    // workspace ≈ 40.3 MB (R1 passed with 40.67 MB)
    char* p = (char*)d_ws;
    unsigned int* bins    = (unsigned int*)p;   p += (size_t)NBKT * CAP * 4;     // 14.0 MB
    unsigned short* h1b   = (unsigned short*)p; p += (size_t)N_NODES * 64 * 2;   // 12.8 MB
    unsigned short* agg2b = (unsigned short*)p; p += (size_t)N_NODES * 64 * 2;   // 12.8 MB
    int* row   = (int*)p;                       p += (size_t)(N_NODES + 1) * 4;  // 0.40 MB
    unsigned short* deg = (unsigned short*)p;   p += (size_t)N_NODES * 2;        // 0.20 MB
    int* gcur  = (int*)p;                       p += NBKT * 4;
    int* gstart= (int*)p;                       p += (N_GRAPHS + 1) * 4;
    unsigned short* wp = (unsigned short*)p;    p += 8192 * 2;                   // 16 KB
    float* pooled = (float*)p;                  p += (size_t)N_GRAPHS * 64 * 4;  // 0.26 MB

    // h2b aliases bins: bins (CSR) is dead after k_gather2
    unsigned short* h2b = (unsigned short*)bins;

    k_prep  <<<38, 256, 0, stream>>>(W2l, W2r, wp, batch, gstart, gcur);
    k_binone<<<NB, 256, 0, stream>>>(src, dst, gcur, bins);
    k_build <<<NBKT, 256, 0, stream>>>(gcur, bins, row, deg, x, W1l, b1, W1r, h1b);

    k_gather2  <<<2048, 256, 0, stream>>>(row, deg, bins, h1b, agg2b);
    k_gemv_mfma<<<(N_NODES + 63) / 64, 256, 0, stream>>>(agg2b, h1b, wp, b2, h2b);
    k_pool3    <<<(N_GRAPHS * 64) / 256, 256, 0, stream>>>(h2b, gstart, pooled);
    k_cls      <<<N_GRAPHS, 64, 0, stream>>>(pooled, Wc, bc, out);
}

// Round 18
// 228.549 us; speedup vs baseline: 1.9118x; 1.0695x over previous
//
#include <hip/hip_runtime.h>

#define N_NODES 100000
#define N_EDGES 3200000
#define N_GRAPHS 1024
#define NCLS 21
#define NBKT 782          // buckets of 128 nodes
#define CAP 4480          // padded bucket capacity (mean 4096, sigma 64 -> +6 sigma)
#define NB 512            // streaming blocks for binning
#define CHUNK 6250        // N_EDGES / NB
#define TROW 72           // LDS tile row stride in ushorts (144B: breaks b128 bank aliasing)

typedef short s8v __attribute__((ext_vector_type(8)));
typedef float f4v __attribute__((ext_vector_type(4)));

__device__ __forceinline__ float bf2f(unsigned short u) {
    return __uint_as_float(((unsigned)u) << 16);
}
__device__ __forceinline__ unsigned short f2bf(float f) {
    unsigned u = __float_as_uint(f);
    unsigned r = 0x7fffu + ((u >> 16) & 1u);   // RNE
    return (unsigned short)((u + r) >> 16);
}
__device__ __forceinline__ float lo2f(unsigned w) { return __uint_as_float(w << 16); }
__device__ __forceinline__ float hi2f(unsigned w) { return __uint_as_float(w & 0xffff0000u); }

// ---- fused prep: wp pack (blocks 0-31), gstart (32-36), gcur init (37) ----
__global__ void k_prep(const float* __restrict__ W2l, const float* __restrict__ W2r,
                       unsigned short* __restrict__ wp,
                       const int* __restrict__ batch, int* __restrict__ gstart,
                       int* __restrict__ gcur) {
    if (blockIdx.x < 32) {
        int tid = blockIdx.x * 256 + threadIdx.x;   // 8192 total
        int frag = tid >> 9;
        int r = tid & 511;
        int L = r >> 3, j = r & 7;
        int kstep = frag >> 2, nt = frag & 3;
        int k = kstep * 32 + (L >> 4) * 8 + j;
        int n = nt * 16 + (L & 15);
        float val = (k < 64) ? W2l[k * 64 + n] : W2r[(k - 64) * 64 + n];
        wp[tid] = f2bf(val);
    } else if (blockIdx.x < 37) {
        int g = (blockIdx.x - 32) * 256 + threadIdx.x;
        if (g > N_GRAPHS) return;
        if (g == N_GRAPHS) { gstart[N_GRAPHS] = N_NODES; return; }
        int lo = 0, hi = N_NODES;
        while (lo < hi) { int m = (lo + hi) >> 1; if (batch[m] < g) lo = m + 1; else hi = m; }
        gstart[g] = lo;
    } else {
        for (int i = threadIdx.x; i < NBKT; i += 256) gcur[i] = i * CAP;
    }
}

// ---- single-pass bin: LDS count -> global run reservation -> LDS scatter ----
__global__ __launch_bounds__(256) void k_binone(const int* __restrict__ src,
                                                const int* __restrict__ dst,
                                                int* __restrict__ gcur,
                                                unsigned int* __restrict__ bins) {
    __shared__ unsigned int ebuf[CHUNK];         // 25 KB
    __shared__ unsigned short bbuf[CHUNK];       // 12.5 KB
    __shared__ int lh[NBKT];
    __shared__ int lbase[NBKT];
    int t = threadIdx.x;
    for (int i = t; i < NBKT; i += 256) lh[i] = 0;
    __syncthreads();
    const int2* s2 = (const int2*)(src + blockIdx.x * CHUNK);
    const int2* d2 = (const int2*)(dst + blockIdx.x * CHUNK);
    for (int i = t; i < CHUNK / 2; i += 256) {
        int2 s = s2[i];
        int2 d = d2[i];
        uint2 pp;
        pp.x = ((unsigned)s.x << 7) | (unsigned)(d.x & 127);
        pp.y = ((unsigned)s.y << 7) | (unsigned)(d.y & 127);
        *(uint2*)(&ebuf[2 * i]) = pp;
        bbuf[2 * i]     = (unsigned short)(d.x >> 7);
        bbuf[2 * i + 1] = (unsigned short)(d.y >> 7);
        atomicAdd(&lh[d.x >> 7], 1);
        atomicAdd(&lh[d.y >> 7], 1);
    }
    __syncthreads();
    for (int i = t; i < NBKT; i += 256)
        lbase[i] = atomicAdd(&gcur[i], lh[i]);
    __syncthreads();
    for (int i = t; i < NBKT; i += 256) lh[i] = lbase[i];
    __syncthreads();
    for (int i = t; i < CHUNK; i += 256) {
        int b = (int)bbuf[i];
        int pos = atomicAdd(&lh[b], 1);
        if (pos < (b + 1) * CAP) bins[pos] = ebuf[i];
    }
}

// ---- per-bucket (128 nodes): slurp -> hist -> scan -> row/deg + CSR + layer-1 ----
__global__ __launch_bounds__(256) void k_build(
    const int* __restrict__ gcur, unsigned int* __restrict__ bins,
    int* __restrict__ row, unsigned short* __restrict__ deg,
    const float* __restrict__ x,
    const float* __restrict__ W1l, const float* __restrict__ b1,
    const float* __restrict__ W1r, unsigned short* __restrict__ h1b) {
    __shared__ unsigned int ebuf[CAP];   // 17.9 KB
    __shared__ int hist[128];
    __shared__ int curs[128];
    __shared__ int lds[128];
    __shared__ float t1[128];
    int k = blockIdx.x, t = threadIdx.x;
    int e0 = k * CAP;
    int cnt = min(gcur[k] - e0, CAP);
    if (t < 128) { hist[t] = 0; t1[t] = 0.0f; }
    __syncthreads();
    for (int i = t; i < cnt; i += 256) {
        unsigned p = bins[e0 + i];
        ebuf[i] = p;
        atomicAdd(&hist[p & 127u], 1);
    }
    __syncthreads();
    if (t < 128) lds[t] = hist[t];
    __syncthreads();
    for (int off = 1; off < 128; off <<= 1) {
        int cur = (t < 128) ? lds[t] : 0;
        int add = (t < 128 && t >= off) ? lds[t - off] : 0;
        __syncthreads();
        if (t < 128) lds[t] = cur + add;
        __syncthreads();
    }
    if (t < 128) {
        int run = e0 + lds[t] - hist[t];
        curs[t] = run;
        int n = k * 128 + t;
        if (n < N_NODES) { row[n] = run; deg[n] = (unsigned short)hist[t]; }
    }
    __syncthreads();
    for (int i = t; i < cnt; i += 256) {
        unsigned p = ebuf[i];
        int slot = (int)(p & 127u);
        int pos = atomicAdd(&curs[slot], 1);
        bins[pos] = p >> 7;
        atomicAdd(&t1[slot], x[p >> 7]);
    }
    __syncthreads();
    for (int i = t; i < 128 * 64; i += 256) {
        int slot = i >> 6, f = i & 63;
        int n = k * 128 + slot;
        if (n >= N_NODES) break;
        float a = t1[slot] / fmaxf((float)hist[slot], 1.0f);
        float v = a * W1l[f] + b1[f] + x[n] * W1r[f];
        h1b[(size_t)n * 64 + f] = f2bf(fmaxf(v, 0.0f));
    }
}

// ---- layer 2 FUSED: gather (per node) -> LDS tile -> MFMA GEMV -> h2b ----
// Wave w owns nodes w*16 .. w*16+15 (6250 waves == 100000 nodes exactly).
__global__ __launch_bounds__(256) void k_l2f(
    const int* __restrict__ row, const unsigned short* __restrict__ deg,
    const unsigned int* __restrict__ csr,
    const unsigned short* __restrict__ h1b,
    const unsigned short* __restrict__ wp, const float* __restrict__ b2,
    unsigned short* __restrict__ h2b) {
    __shared__ unsigned short tile[4][16 * TROW];   // 9 KB
    int wid = threadIdx.x >> 6;
    int w = blockIdx.x * 4 + wid;
    if (w >= N_NODES / 16) return;
    int L = threadIdx.x & 63;
    int fo = L & 7;
    int es = L >> 3;
    int fown = fo * 8 + es;            // feature this lane owns post-reduce
    unsigned short* tw = tile[wid];

    for (int t = 0; t < 16; t++) {
        int n = w * 16 + t;
        int r0 = row[n];
        int dn = (int)deg[n];
        int r1 = r0 + dn;
        float a0 = 0.f, a1 = 0.f, a2 = 0.f, a3 = 0.f,
              a4 = 0.f, a5 = 0.f, a6 = 0.f, a7 = 0.f;
        int base = r0;
        for (; base + 32 <= r1; base += 32) {
            int sA = (int)csr[base + es];
            int sB = (int)csr[base + 8 + es];
            int sC = (int)csr[base + 16 + es];
            int sD = (int)csr[base + 24 + es];
            uint4 dA = *(const uint4*)(h1b + (size_t)sA * 64 + fo * 8);
            uint4 dB = *(const uint4*)(h1b + (size_t)sB * 64 + fo * 8);
            uint4 dC = *(const uint4*)(h1b + (size_t)sC * 64 + fo * 8);
            uint4 dD = *(const uint4*)(h1b + (size_t)sD * 64 + fo * 8);
            a0 += lo2f(dA.x); a1 += hi2f(dA.x); a2 += lo2f(dA.y); a3 += hi2f(dA.y);
            a4 += lo2f(dA.z); a5 += hi2f(dA.z); a6 += lo2f(dA.w); a7 += hi2f(dA.w);
            a0 += lo2f(dB.x); a1 += hi2f(dB.x); a2 += lo2f(dB.y); a3 += hi2f(dB.y);
            a4 += lo2f(dB.z); a5 += hi2f(dB.z); a6 += lo2f(dB.w); a7 += hi2f(dB.w);
            a0 += lo2f(dC.x); a1 += hi2f(dC.x); a2 += lo2f(dC.y); a3 += hi2f(dC.y);
            a4 += lo2f(dC.z); a5 += hi2f(dC.z); a6 += lo2f(dC.w); a7 += hi2f(dC.w);
            a0 += lo2f(dD.x); a1 += hi2f(dD.x); a2 += lo2f(dD.y); a3 += hi2f(dD.y);
            a4 += lo2f(dD.z); a5 += hi2f(dD.z); a6 += lo2f(dD.w); a7 += hi2f(dD.w);
        }
        for (; base + 16 <= r1; base += 16) {
            int sA = (int)csr[base + es];
            int sB = (int)csr[base + 8 + es];
            uint4 dA = *(const uint4*)(h1b + (size_t)sA * 64 + fo * 8);
            uint4 dB = *(const uint4*)(h1b + (size_t)sB * 64 + fo * 8);
            a0 += lo2f(dA.x); a1 += hi2f(dA.x); a2 += lo2f(dA.y); a3 += hi2f(dA.y);
            a4 += lo2f(dA.z); a5 += hi2f(dA.z); a6 += lo2f(dA.w); a7 += hi2f(dA.w);
            a0 += lo2f(dB.x); a1 += hi2f(dB.x); a2 += lo2f(dB.y); a3 += hi2f(dB.y);
            a4 += lo2f(dB.z); a5 += hi2f(dB.z); a6 += lo2f(dB.w); a7 += hi2f(dB.w);
        }
        for (; base < r1; base += 8) {
            int e = base + es;
            bool act = e < r1;
            int sA = (int)csr[act ? e : r1 - 1];
            uint4 d = *(const uint4*)(h1b + (size_t)sA * 64 + fo * 8);
            unsigned m = act ? 0xffffffffu : 0u;
            d.x &= m; d.y &= m; d.z &= m; d.w &= m;
            a0 += lo2f(d.x); a1 += hi2f(d.x); a2 += lo2f(d.y); a3 += hi2f(d.y);
            a4 += lo2f(d.z); a5 += hi2f(d.z); a6 += lo2f(d.w); a7 += hi2f(d.w);
        }
        {
            bool hi = (es & 4) != 0;
            float s0 = hi ? a0 : a4, s1 = hi ? a1 : a5, s2 = hi ? a2 : a6, s3 = hi ? a3 : a7;
            float r0v = __shfl_xor(s0, 32, 64);
            float r1v = __shfl_xor(s1, 32, 64);
            float r2v = __shfl_xor(s2, 32, 64);
            float r3v = __shfl_xor(s3, 32, 64);
            a0 = (hi ? a4 : a0) + r0v;
            a1 = (hi ? a5 : a1) + r1v;
            a2 = (hi ? a6 : a2) + r2v;
            a3 = (hi ? a7 : a3) + r3v;
        }
        {
            bool hi = (es & 2) != 0;
            float s0 = hi ? a0 : a2, s1 = hi ? a1 : a3;
            float r0v = __shfl_xor(s0, 16, 64);
            float r1v = __shfl_xor(s1, 16, 64);
            a0 = (hi ? a2 : a0) + r0v;
            a1 = (hi ? a3 : a1) + r1v;
        }
        {
            bool hi = (es & 1) != 0;
            float s0 = hi ? a0 : a1;
            float r0v = __shfl_xor(s0, 8, 64);
            a0 = (hi ? a1 : a0) + r0v;
        }
        float inv = 1.0f / fmaxf((float)dn, 1.0f);
        tw[t * TROW + fown] = f2bf(a0 * inv);   // 2B/lane, 2-way bank = free
    }

    // ---- MFMA phase: A from LDS tile (agg2) + global h1b rows; B from wp ----
    int m = L & 15, q = L >> 4;
    int nrow = w * 16 + m;

    const s8v a0 = *(const s8v*)(tw + m * TROW + q * 8);
    const s8v a1 = *(const s8v*)(tw + m * TROW + 32 + q * 8);
    const s8v a2 = *(const s8v*)(h1b + (size_t)nrow * 64 + q * 8);
    const s8v a3 = *(const s8v*)(h1b + (size_t)nrow * 64 + 32 + q * 8);

#define LOADB(i) s8v B##i = *(const s8v*)(wp + (i) * 512 + L * 8)
    LOADB(0); LOADB(1); LOADB(2); LOADB(3);
    LOADB(4); LOADB(5); LOADB(6); LOADB(7);
    LOADB(8); LOADB(9); LOADB(10); LOADB(11);
    LOADB(12); LOADB(13); LOADB(14); LOADB(15);
#undef LOADB

    f4v acc0 = {0.f, 0.f, 0.f, 0.f}, acc1 = acc0, acc2 = acc0, acc3 = acc0;
    acc0 = __builtin_amdgcn_mfma_f32_16x16x32_bf16(a0, B0,  acc0, 0, 0, 0);
    acc0 = __builtin_amdgcn_mfma_f32_16x16x32_bf16(a1, B4,  acc0, 0, 0, 0);
    acc0 = __builtin_amdgcn_mfma_f32_16x16x32_bf16(a2, B8,  acc0, 0, 0, 0);
    acc0 = __builtin_amdgcn_mfma_f32_16x16x32_bf16(a3, B12, acc0, 0, 0, 0);
    acc1 = __builtin_amdgcn_mfma_f32_16x16x32_bf16(a0, B1,  acc1, 0, 0, 0);
    acc1 = __builtin_amdgcn_mfma_f32_16x16x32_bf16(a1, B5,  acc1, 0, 0, 0);
    acc1 = __builtin_amdgcn_mfma_f32_16x16x32_bf16(a2, B9,  acc1, 0, 0, 0);
    acc1 = __builtin_amdgcn_mfma_f32_16x16x32_bf16(a3, B13, acc1, 0, 0, 0);
    acc2 = __builtin_amdgcn_mfma_f32_16x16x32_bf16(a0, B2,  acc2, 0, 0, 0);
    acc2 = __builtin_amdgcn_mfma_f32_16x16x32_bf16(a1, B6,  acc2, 0, 0, 0);
    acc2 = __builtin_amdgcn_mfma_f32_16x16x32_bf16(a2, B10, acc2, 0, 0, 0);
    acc2 = __builtin_amdgcn_mfma_f32_16x16x32_bf16(a3, B14, acc2, 0, 0, 0);
    acc3 = __builtin_amdgcn_mfma_f32_16x16x32_bf16(a0, B3,  acc3, 0, 0, 0);
    acc3 = __builtin_amdgcn_mfma_f32_16x16x32_bf16(a1, B7,  acc3, 0, 0, 0);
    acc3 = __builtin_amdgcn_mfma_f32_16x16x32_bf16(a2, B11, acc3, 0, 0, 0);
    acc3 = __builtin_amdgcn_mfma_f32_16x16x32_bf16(a3, B15, acc3, 0, 0, 0);

    int fcol = L & 15;
    float bia0 = b2[fcol], bia1 = b2[16 + fcol], bia2 = b2[32 + fcol], bia3 = b2[48 + fcol];
    int rbase = w * 16 + q * 4;
#pragma unroll
    for (int r = 0; r < 4; r++) {
        size_t o = (size_t)(rbase + r) * 64 + fcol;
        h2b[o]      = f2bf(fmaxf(acc0[r] + bia0, 0.0f));
        h2b[o + 16] = f2bf(fmaxf(acc1[r] + bia1, 0.0f));
        h2b[o + 32] = f2bf(fmaxf(acc2[r] + bia2, 0.0f));
        h2b[o + 48] = f2bf(fmaxf(acc3[r] + bia3, 0.0f));
    }
}

// ---- head: block per graph — pool h2 rows + classify, no global intermediates ----
__global__ __launch_bounds__(256) void k_head(
    const unsigned short* __restrict__ h2b, const int* __restrict__ gstart,
    const float* __restrict__ Wc, const float* __restrict__ bc,
    float* __restrict__ out) {
    __shared__ float part[4][64];
    __shared__ float rowv[64];
    int g = blockIdx.x;
    int wid = threadIdx.x >> 6;
    int f = threadIdx.x & 63;
    int ns = gstart[g], ne = gstart[g + 1];
    float s = 0.0f;
    int n = ns + wid;
    for (; n + 12 < ne; n += 16) {
        float v0 = bf2f(h2b[(size_t)(n)      * 64 + f]);
        float v1 = bf2f(h2b[(size_t)(n + 4)  * 64 + f]);
        float v2 = bf2f(h2b[(size_t)(n + 8)  * 64 + f]);
        float v3 = bf2f(h2b[(size_t)(n + 12) * 64 + f]);
        s += (v0 + v1) + (v2 + v3);
    }
    for (; n < ne; n += 4) s += bf2f(h2b[(size_t)n * 64 + f]);
    part[wid][f] = s;
    __syncthreads();
    if (threadIdx.x < 64) {
        float tot = part[0][f] + part[1][f] + part[2][f] + part[3][f];
        rowv[f] = tot / fmaxf((float)(ne - ns), 1.0f);
    }
    __syncthreads();
    if (threadIdx.x < NCLS) {
        float acc = bc[threadIdx.x];
#pragma unroll
        for (int kk = 0; kk < 64; kk++) acc += rowv[kk] * Wc[kk * NCLS + threadIdx.x];
        out[g * NCLS + threadIdx.x] = acc;
    }
}

extern "C" void kernel_launch(void* const* d_in, const int* in_sizes, int n_in,
                              void* d_out, int out_size, void* d_ws, size_t ws_size,
                              hipStream_t stream) {
    const float* x     = (const float*)d_in[0];
    const int*   eidx  = (const int*)d_in[1];
    const int*   batch = (const int*)d_in[2];
    const float* W1l   = (const float*)d_in[3];
    const float* b1    = (const float*)d_in[4];
    const float* W1r   = (const float*)d_in[5];
    const float* W2l   = (const float*)d_in[6];
    const float* b2    = (const float*)d_in[7];
    const float* W2r   = (const float*)d_in[8];
    const float* Wc    = (const float*)d_in[9];
    const float* bc    = (const float*)d_in[10];
    float* out = (float*)d_out;

    const int* src = eidx;
    const int* dst = eidx + N_EDGES;

    // workspace ≈ 40.3 MB (R16 passed with this footprint)
    char* p = (char*)d_ws;
    unsigned int* bins  = (unsigned int*)p;     p += (size_t)NBKT * CAP * 4;     // 14.0 MB
    unsigned short* h1b = (unsigned short*)p;   p += (size_t)N_NODES * 64 * 2;   // 12.8 MB
    unsigned short* h2b = (unsigned short*)p;   p += (size_t)N_NODES * 64 * 2;   // 12.8 MB
    int* row   = (int*)p;                       p += (size_t)(N_NODES + 1) * 4;  // 0.40 MB
    unsigned short* deg = (unsigned short*)p;   p += (size_t)N_NODES * 2;        // 0.20 MB
    int* gcur  = (int*)p;                       p += NBKT * 4;
    int* gstart= (int*)p;                       p += (N_GRAPHS + 1) * 4;
    unsigned short* wp = (unsigned short*)p;    p += 8192 * 2;                   // 16 KB

    k_prep  <<<38, 256, 0, stream>>>(W2l, W2r, wp, batch, gstart, gcur);
    k_binone<<<NB, 256, 0, stream>>>(src, dst, gcur, bins);
    k_build <<<NBKT, 256, 0, stream>>>(gcur, bins, row, deg, x, W1l, b1, W1r, h1b);
    k_l2f   <<<(N_NODES / 16 + 3) / 4, 256, 0, stream>>>(row, deg, bins, h1b, wp, b2, h2b);
    k_head  <<<N_GRAPHS, 256, 0, stream>>>(h2b, gstart, Wc, bc, out);
}